// Round 3
// baseline (936.857 us; speedup 1.0000x reference)
//
#include <hip/hip_runtime.h>

typedef unsigned short u16;
typedef _Float16 f16;
typedef _Float16 f16x8 __attribute__((ext_vector_type(8)));
typedef _Float16 f16x2 __attribute__((ext_vector_type(2)));
typedef float f32x4 __attribute__((ext_vector_type(4)));

#define AS1 __attribute__((address_space(1)))
#define AS3 __attribute__((address_space(3)))

constexpr int N_NODES = 8000;
constexpr int N_EDGES = 64000;
constexpr int F_IN    = 2560;   // in channels (== H*C, both layers)
constexpr int HEADS   = 8;
constexpr int CPH     = 320;    // channels per head
constexpr int HC      = 2560;   // HEADS*CPH
constexpr int NW      = 5120;   // fused GEMM output width (XL | XR)
constexpr int NGRAPH  = 16;
constexpr float SLOPE = 0.2f;

// ---------------- f32 -> f16 bulk convert (n divisible by 1024) ----------------
__global__ __launch_bounds__(256)
void cvt_f32_f16(const float* __restrict__ in, f16* __restrict__ out, int n)
{
  const int i = (blockIdx.x * 256 + threadIdx.x) * 4;
  if (i >= n) return;
  const float4 v = *(const float4*)(in + i);
  f16 o[4] = {(f16)v.x, (f16)v.y, (f16)v.z, (f16)v.w};
  *(ushort4*)(out + i) = *(const ushort4*)o;
}

// ------ weight transpose + convert: in f32 [R=2560][C=2560] -> out f16 [C][R] ------
__global__ __launch_bounds__(256)
void transpose_w(const float* __restrict__ in, f16* __restrict__ out)
{
  __shared__ u16 tile[64][66];     // +2 pad to break bank stride
  const int bx = blockIdx.x * 64;  // col tile (input)
  const int by = blockIdx.y * 64;  // row tile (input)
  const int tx = threadIdx.x & 63;
  const int ty = threadIdx.x >> 6;
  #pragma unroll
  for (int i = ty; i < 64; i += 4) {
    f16 h = (f16)in[(size_t)(by + i) * HC + bx + tx];
    u16 u; __builtin_memcpy(&u, &h, 2);
    tile[i][tx] = u;
  }
  __syncthreads();
  #pragma unroll
  for (int i = ty; i < 64; i += 4) {
    u16 u = tile[tx][i];
    f16 h; __builtin_memcpy(&h, &u, 2);
    out[(size_t)(bx + i) * F_IN + by + tx] = h;
  }
}

// ---- Fused GEMM: [XL|XR][M,5120](f16) = A[M,K](f16) @ BT[5120,K]^T + bias; fp32 acc ----
// 8-phase pipelined 256x256 tile, BK=64, 512 threads / 8 waves (2M x 4N),
// per-wave 128x64 output (8x4 16x16x32 fragments). 128 KiB LDS double buffer.
// Counted vmcnt(4) at phases 4/8 only; raw s_barrier; setprio around MFMA.
// Per-row XOR-8 16B-chunk swizzle on LDS (conflict-free, verified 0 conflicts).
// XCD-local 2D chunk grid map (FETCH 162 MB = ideal); LDS round-trip epilogue
// (WRITE 80 MB = ideal). Unchanged from round 2 (measured 221 us, MfmaUtil 42.5%;
// ~17% of the remaining gap is the 640-tiles/256-CU = 3-round scheduling tail,
// not fixable at this tile geometry).
__global__ __launch_bounds__(512, 2)
void gemm_fused(const f16* __restrict__ A, const f16* __restrict__ BT,
                const float* __restrict__ bl, const float* __restrict__ br,
                f16* __restrict__ XL, f16* __restrict__ XR)
{
  __shared__ __align__(16) f16 sm[65536];   // 128 KiB
  f16* const sA0 = sm;
  f16* const sA1 = sm + 16384;
  f16* const sB0 = sm + 32768;
  f16* const sB1 = sm + 49152;

  const int t    = threadIdx.x;
  const int lane = t & 63;
  const int wave = t >> 6;

  // XCD-local 2D chunk: xcd = bid%8 owns m-tiles [4*xcd, 4*xcd+3] x n 0..19
  const int bid0 = (int)blockIdx.x;      // 640 = 32 m-tiles x 20 n-tiles
  const int xcd  = bid0 & 7;
  const int ic   = bid0 >> 3;            // 0..79, dispatch order within XCD
  const int m0   = (xcd * 4 + (ic & 3)) * 256;   // m-fastest: A panels L2-pinned
  const int n0   = (ic >> 2) * 256;

  const int fm = (wave >> 2) * 128;     // 0 / 128
  const int fn = (wave & 3) * 64;       // 0..192
  const int ml = lane & 15;
  const int lq = lane >> 4;

  auto stageA = [&](f16* D, int half, int kt) {
    const int k0 = kt * 64;
    #pragma unroll
    for (int jj = 0; jj < 2; ++jj) {
      const int s  = jj * 512 + t;
      const int r  = s >> 3;
      const int lc = (s & 7) ^ (r & 7);
      int gr = m0 + half * 128 + r;
      gr = (gr < N_NODES) ? gr : (N_NODES - 1);   // clamp pad rows (stores guarded)
      const f16* g = A + (size_t)gr * F_IN + k0 + lc * 8;
      __builtin_amdgcn_global_load_lds((AS1 const void*)g,
                                       (AS3 void*)(D + half * 8192 + s * 8), 16, 0, 0);
    }
  };
  auto stageB = [&](f16* D, int half, int kt) {
    const int k0 = kt * 64;
    #pragma unroll
    for (int jj = 0; jj < 2; ++jj) {
      const int s  = jj * 512 + t;
      const int r  = s >> 3;
      const int lc = (s & 7) ^ (r & 7);
      const f16* g = BT + (size_t)(n0 + half * 128 + r) * F_IN + k0 + lc * 8;
      __builtin_amdgcn_global_load_lds((AS1 const void*)g,
                                       (AS3 void*)(D + half * 8192 + s * 8), 16, 0, 0);
    }
  };
  auto ldA = [&](const f16* S, int i, int kk) -> f16x8 {
    const int row = fm + i * 16 + ml;
    const int p   = (kk * 4 + lq) ^ (row & 7);
    return *(const f16x8*)(S + row * 64 + p * 8);
  };
  auto ldB = [&](const f16* S, int j, int kk) -> f16x8 {
    const int row = fn + j * 16 + ml;
    const int p   = (kk * 4 + lq) ^ (row & 7);
    return *(const f16x8*)(S + row * 64 + p * 8);
  };

  f32x4 acc[8][4] = {};
  f16x8 bf[4][2];

#define MMROW(i, A0_, A1_)                                                                   \
    _Pragma("unroll")                                                                        \
    for (int j = 0; j < 4; ++j) {                                                            \
      acc[i][j] = __builtin_amdgcn_mfma_f32_16x16x32_f16(A0_, bf[j][0], acc[i][j], 0, 0, 0); \
      acc[i][j] = __builtin_amdgcn_mfma_f32_16x16x32_f16(A1_, bf[j][1], acc[i][j], 0, 0, 0); \
    }

#define PHASE(SA, q, STG)                          \
  {                                                \
    const f16x8 p00 = ldA(SA, 2*(q),     0);       \
    const f16x8 p01 = ldA(SA, 2*(q),     1);       \
    const f16x8 p10 = ldA(SA, 2*(q) + 1, 0);       \
    const f16x8 p11 = ldA(SA, 2*(q) + 1, 1);       \
    STG;                                           \
    __builtin_amdgcn_s_barrier();                  \
    __builtin_amdgcn_sched_barrier(0);             \
    __builtin_amdgcn_s_setprio(1);                 \
    MMROW(2*(q),     p00, p01)                     \
    MMROW(2*(q) + 1, p10, p11)                     \
    __builtin_amdgcn_s_setprio(0);                 \
  }

#define ENDPH() { __builtin_amdgcn_s_barrier(); __builtin_amdgcn_sched_barrier(0); }
#define LOADB(SB) { _Pragma("unroll") for (int j = 0; j < 4; ++j) { bf[j][0] = ldB(SB, j, 0); bf[j][1] = ldB(SB, j, 1); } }

  // prologue: tile0 A+B, tile1 B; 12 loads, wait oldest 8 (tile0 complete)
  stageA(sA0, 0, 0); stageA(sA0, 1, 0);
  stageB(sB0, 0, 0); stageB(sB0, 1, 0);
  stageB(sB1, 0, 1); stageB(sB1, 1, 1);
  asm volatile("s_waitcnt vmcnt(4)" ::: "memory");
  __builtin_amdgcn_s_barrier();
  __builtin_amdgcn_sched_barrier(0);

  for (int it = 0; it < 20; ++it) {        // 40 K-tiles, 2 per iteration
    const int T  = 2 * it;
    const int t1 = T + 1;                              // <= 39 always
    const int t2 = (T + 2 < 40) ? T + 2 : 39;          // clamp: uniform load counts,
    const int t3 = (T + 3 < 40) ? T + 3 : 39;          // dup stages land in dead bufs

    // ---- K-tile T from buf0 ----
    LOADB(sB0)
    PHASE(sA0, 0, stageA(sA1, 0, t1)) ENDPH()
    PHASE(sA0, 1, stageA(sA1, 1, t1)) ENDPH()
    PHASE(sA0, 2, stageB(sB0, 0, t2)) ENDPH()
    PHASE(sA0, 3, stageB(sB0, 1, t2))
    asm volatile("s_waitcnt vmcnt(4)" ::: "memory");
    ENDPH()
    // ---- K-tile T+1 from buf1 ----
    LOADB(sB1)
    PHASE(sA1, 0, stageA(sA0, 0, t2)) ENDPH()
    PHASE(sA1, 1, stageA(sA0, 1, t2)) ENDPH()
    PHASE(sA1, 2, stageB(sB1, 0, t3)) ENDPH()
    PHASE(sA1, 3, stageB(sB1, 1, t3))
    asm volatile("s_waitcnt vmcnt(4)" ::: "memory");
    ENDPH()
  }

#undef MMROW
#undef PHASE
#undef ENDPH
#undef LOADB

  // ---- epilogue: drain pending stages, then LDS round-trip for coalesced stores ----
  asm volatile("s_waitcnt vmcnt(0)" ::: "memory");
  __builtin_amdgcn_s_barrier();

  const bool left = (n0 < HC);
  f16* __restrict__ OUT = left ? XL : XR;
  const float* __restrict__ bias = left ? bl : br;
  const int nb = left ? n0 : (n0 - HC);
  const int rg = (lane >> 4) * 4;
  f16* const wbase = sm + wave * 8192;   // 16 KB per wave (128 rows x 64 cols)

  #pragma unroll
  for (int j = 0; j < 4; ++j) {
    const float bv = bias[nb + fn + j * 16 + ml];
    #pragma unroll
    for (int i = 0; i < 8; ++i) {
      #pragma unroll
      for (int r = 0; r < 4; ++r) {
        const int row = i * 16 + rg + r;
        const int col = j * 16 + ml;
        const int pc  = (col >> 3) ^ (row & 7);
        wbase[row * 64 + pc * 8 + (col & 7)] = (f16)(acc[i][j][r] + bv);
      }
    }
  }
  __syncthreads();
  #pragma unroll
  for (int it = 0; it < 16; ++it) {
    const int row = it * 8 + (lane >> 3);
    const int ch  = lane & 7;
    const int pc  = ch ^ (row & 7);
    const f16x8 v = *(const f16x8*)(wbase + row * 64 + pc * 8);
    const int gm = m0 + fm + row;
    if (gm < N_NODES)
      *(f16x8*)(OUT + (size_t)gm * HC + nb + fn + ch * 8) = v;
  }
}

// ---------------- CSR build ----------------
__global__ __launch_bounds__(256)
void count_edges(const int* __restrict__ dst, int* __restrict__ counts)
{
  const int e = blockIdx.x * 256 + threadIdx.x;
  if (e < N_EDGES) atomicAdd(&counts[dst[e]], 1);
}

__global__ __launch_bounds__(256)
void scan_offsets(const int* __restrict__ counts, int* __restrict__ offs, int* __restrict__ cur)
{
  __shared__ int wtot[4];
  const int t = threadIdx.x;
  const int lane = t & 63, wave = t >> 6;
  const int base = t * 32;
  int loc[32];
  int run = 0;
  #pragma unroll
  for (int i = 0; i < 32; ++i) {
    const int idx = base + i;
    const int v = (idx < N_NODES) ? counts[idx] : 0;
    loc[i] = run;
    run += v;
  }
  int incl = run;
  #pragma unroll
  for (int off = 1; off < 64; off <<= 1) {
    int y = __shfl_up(incl, off, 64);
    if (lane >= off) incl += y;
  }
  const int excl = incl - run;
  if (lane == 63) wtot[wave] = incl;
  __syncthreads();
  int wb = 0;
  for (int wv = 0; wv < wave; ++wv) wb += wtot[wv];
  const int mybase = wb + excl;
  #pragma unroll
  for (int i = 0; i < 32; ++i) {
    const int idx = base + i;
    if (idx < N_NODES) { offs[idx] = mybase + loc[i]; cur[idx] = mybase + loc[i]; }
  }
  if (t == 255) offs[N_NODES] = wb + incl;
}

// fill CSR with PACKED edge meta {src, eattr_bits}: kills the eids->src/eattr
// double-indirection in the edge kernel (one 8B load replaces a 3-load chain).
__global__ __launch_bounds__(256)
void fill_csr(const int* __restrict__ dst, const int* __restrict__ srcv,
              const float* __restrict__ ea, int* __restrict__ cur,
              int2* __restrict__ ecsr)
{
  const int e = blockIdx.x * 256 + threadIdx.x;
  if (e < N_EDGES) {
    const int p = atomicAdd(&cur[dst[e]], 1);
    ecsr[p] = make_int2(srcv[e], __float_as_int(ea[e]));
  }
}

// ---- Fused edge phase: scores + online segment-softmax + aggregation, one pass ----
// Per half-wave = one head. Lane l32 owns channels {l32*8..+7} U {256+2*l32,+1}.
// PAIR-processed (2 edges/iter, fused max3 + 2-exp softmax update, ~15% less VALU,
// half the serial softmax chains) with 4-slot ping-pong prefetch: rows for pairs
// i+2/i+3 and packed meta for i+4/i+5 in flight while computing pairs i/i+1.
// No rotate-copy reads a load issued less than one compute-span earlier.
__global__ __launch_bounds__(256)
void gat_edge_fused(const f16* __restrict__ XL, const f16* __restrict__ XR,
                    const float* __restrict__ We, const float* __restrict__ att,
                    const int2* __restrict__ ecsr, const int* __restrict__ offs,
                    const float* __restrict__ bias,
                    f16* __restrict__ out)
{
  const int n    = blockIdx.x;
  const int t    = threadIdx.x;
  const int wave = t >> 6;
  const int lane = t & 63;
  const int half = lane >> 5;
  const int l32  = lane & 31;
  const int h    = wave * 2 + half;
  const int c8   = h * CPH + l32 * 8;        // 8 contiguous channels (16B aligned)
  const int c2   = h * CPH + 256 + l32 * 2;  // 2 contiguous channels (4B aligned)

  float xr[10], wv[10], av[10];
  {
    const f16x8 v8 = *(const f16x8*)(XR + (size_t)n * HC + c8);
    const f16x2 v2 = *(const f16x2*)(XR + (size_t)n * HC + c2);
    #pragma unroll
    for (int k = 0; k < 8; ++k) xr[k] = (float)v8[k];
    xr[8] = (float)v2[0]; xr[9] = (float)v2[1];
  }
  {
    const float4 w0 = *(const float4*)(We + c8);
    const float4 w1 = *(const float4*)(We + c8 + 4);
    const float4 a0 = *(const float4*)(att + c8);
    const float4 a1 = *(const float4*)(att + c8 + 4);
    wv[0]=w0.x; wv[1]=w0.y; wv[2]=w0.z; wv[3]=w0.w;
    wv[4]=w1.x; wv[5]=w1.y; wv[6]=w1.z; wv[7]=w1.w;
    av[0]=a0.x; av[1]=a0.y; av[2]=a0.z; av[3]=a0.w;
    av[4]=a1.x; av[5]=a1.y; av[6]=a1.z; av[7]=a1.w;
    wv[8] = We[c2]; wv[9] = We[c2 + 1];
    av[8] = att[c2]; av[9] = att[c2 + 1];
  }

  float m = -3.0e38f, l = 0.f;
  float acc[10];
  #pragma unroll
  for (int k = 0; k < 10; ++k) acc[k] = 0.f;

  const int b = offs[n], e = offs[n + 1];
  const int d = e - b;
  if (d > 0) {
    const int np = (d + 1) >> 1;   // pairs

    auto ldmeta = [&](int pi, int2* mm) {
      pi = (pi < np) ? pi : (np - 1);
      const int q0 = b + 2 * pi;
      const int q1 = q0 + 1;
      mm[0] = ecsr[q0];
      mm[1] = ecsr[(q1 < e) ? q1 : q0];
    };
    auto ldrows = [&](const int2* mm, f16x8* v8, f16x2* v2) {
      const f16* r0 = XL + (size_t)mm[0].x * HC;
      const f16* r1 = XL + (size_t)mm[1].x * HC;
      v8[0] = *(const f16x8*)(r0 + c8);
      v8[1] = *(const f16x8*)(r1 + c8);
      v2[0] = *(const f16x2*)(r0 + c2);
      v2[1] = *(const f16x2*)(r1 + c2);
    };
    auto compute_pair = [&](const f16x8* V8, const f16x2* V2, const int2* M, int i) {
      const bool v1 = (b + 2 * i + 1) < e;
      const float ea0 = __int_as_float(M[0].y);
      const float ea1 = __int_as_float(M[1].y);
      float xl0[10], xl1[10];
      #pragma unroll
      for (int k = 0; k < 8; ++k) { xl0[k] = (float)V8[0][k]; xl1[k] = (float)V8[1][k]; }
      xl0[8] = (float)V2[0][0]; xl0[9] = (float)V2[0][1];
      xl1[8] = (float)V2[1][0]; xl1[9] = (float)V2[1][1];
      float p0 = 0.f, p1 = 0.f;
      #pragma unroll
      for (int k = 0; k < 10; ++k) {
        float a0 = xl0[k] + xr[k] + ea0 * wv[k];
        float a1 = xl1[k] + xr[k] + ea1 * wv[k];
        a0 = (a0 > 0.f) ? a0 : SLOPE * a0;
        a1 = (a1 > 0.f) ? a1 : SLOPE * a1;
        p0 += a0 * av[k];
        p1 += a1 * av[k];
      }
      #pragma unroll
      for (int msk = 16; msk >= 1; msk >>= 1) {
        p0 += __shfl_xor(p0, msk, 64);
        p1 += __shfl_xor(p1, msk, 64);
      }
      const float s1v   = v1 ? p1 : -3.0e38f;       // exp(-3e38 - mn) flushes to 0
      const float mn    = fmaxf(m, fmaxf(p0, s1v));
      const float scale = __expf(m - mn);
      const float w0    = __expf(p0 - mn);
      const float w1    = __expf(s1v - mn);
      l = l * scale + w0 + w1;
      #pragma unroll
      for (int k = 0; k < 10; ++k) acc[k] = acc[k] * scale + w0 * xl0[k] + w1 * xl1[k];
      m = mn;
    };

    int2 mA[2], mB[2], mC[2], mD[2];
    f16x8 A8[2], B8[2], C8r[2], D8r[2];
    f16x2 A2[2], B2[2], C2r[2], D2r[2];
    ldmeta(0, mA); ldmeta(1, mB);
    ldrows(mA, A8, A2);
    ldrows(mB, B8, B2);
    ldmeta(2, mC); ldmeta(3, mD);

    int i = 0;
    for (; i + 1 < np; i += 2) {
      ldrows(mC, C8r, C2r);          // rows for pair i+2 (meta landed >=1 iter ago)
      compute_pair(A8, A2, mA, i);
      ldrows(mD, D8r, D2r);          // rows for pair i+3
      compute_pair(B8, B2, mB, i + 1);
      mA[0] = mC[0]; mA[1] = mC[1];
      mB[0] = mD[0]; mB[1] = mD[1];
      ldmeta(i + 4, mC); ldmeta(i + 5, mD);
      A8[0] = C8r[0]; A8[1] = C8r[1]; A2[0] = C2r[0]; A2[1] = C2r[1];
      B8[0] = D8r[0]; B8[1] = D8r[1]; B2[0] = D2r[0]; B2[1] = D2r[1];
    }
    if (i < np) compute_pair(A8, A2, mA, i);   // odd pair count tail
  }

  const float inv = (l > 0.f) ? 1.f / l : 0.f;   // deg-0 node -> out = bias (matches ref)
  f16x8 s8;
  #pragma unroll
  for (int k = 0; k < 8; ++k) s8[k] = (f16)(acc[k] * inv + bias[c8 + k]);
  f16x2 s2;
  s2[0] = (f16)(acc[8] * inv + bias[c2]);
  s2[1] = (f16)(acc[9] * inv + bias[c2 + 1]);
  *(f16x8*)(out + (size_t)n * HC + c8) = s8;
  *(f16x2*)(out + (size_t)n * HC + c2) = s2;
}

// ---------------- global mean pool (batch is sorted), f16 in, f32 out ----------------
__global__ __launch_bounds__(256)
void pool_kernel(const f16* __restrict__ Hm, const int* __restrict__ batch, float* __restrict__ out)
{
  __shared__ int se[2];
  const int g = blockIdx.x;
  const int chunk = blockIdx.y;
  const int t = threadIdx.x;
  if (t < 2) {
    const int target = g + t;
    int lo = 0, hi = N_NODES;
    while (lo < hi) { const int mid = (lo + hi) >> 1; if (batch[mid] < target) lo = mid + 1; else hi = mid; }
    se[t] = lo;
  }
  __syncthreads();
  const int s0 = se[0], s1 = se[1];
  const int c = chunk * 256 + t;
  float sum = 0.f;
  for (int n = s0; n < s1; ++n) sum += (float)Hm[(size_t)n * HC + c];
  int cnt = s1 - s0; if (cnt < 1) cnt = 1;
  out[g * HC + c] = sum / (float)cnt;
}

// ---------------- host: one GATv2 layer (A f16 -> OUT f16) ----------------
static void run_layer(const f16* A, const float* Wl, const float* bl,
                      const float* Wr, const float* br,
                      const float* We, const float* att, const float* bias,
                      f16* WT, f16* XL, f16* XR,
                      const int* offs, const int2* ecsr, f16* OUT, hipStream_t stream)
{
  dim3 tgrid(HC / 64, F_IN / 64);
  transpose_w<<<tgrid, 256, 0, stream>>>(Wl, WT);
  transpose_w<<<tgrid, 256, 0, stream>>>(Wr, WT + (size_t)HC * F_IN);
  gemm_fused<<<32 * (NW / 256), 512, 0, stream>>>(A, WT, bl, br, XL, XR);
  gat_edge_fused<<<N_NODES, 256, 0, stream>>>(XL, XR, We, att, ecsr, offs, bias, OUT);
}

extern "C" void kernel_launch(void* const* d_in, const int* in_sizes, int n_in,
                              void* d_out, int out_size, void* d_ws, size_t ws_size,
                              hipStream_t stream)
{
  const float* x     = (const float*)d_in[0];
  const int*   eidx  = (const int*)d_in[1];
  const float* eattr = (const float*)d_in[2];
  const int*   batch = (const int*)d_in[3];
  const float* Wl1  = (const float*)d_in[4];
  const float* bl1  = (const float*)d_in[5];
  const float* Wr1  = (const float*)d_in[6];
  const float* br1  = (const float*)d_in[7];
  const float* We1  = (const float*)d_in[8];
  const float* att1 = (const float*)d_in[9];
  const float* bias1= (const float*)d_in[10];
  const float* Wl2  = (const float*)d_in[11];
  const float* bl2  = (const float*)d_in[12];
  const float* Wr2  = (const float*)d_in[13];
  const float* br2  = (const float*)d_in[14];
  const float* We2  = (const float*)d_in[15];
  const float* att2 = (const float*)d_in[16];
  const float* bias2= (const float*)d_in[17];
  float* out = (float*)d_out;

  const int* src = eidx;
  const int* dst = eidx + N_EDGES;

  char* w = (char*)d_ws;
  auto take = [&](size_t b) { char* p = w; w += (b + 255) & ~(size_t)255; return p; };
  f16*   Xh    = (f16*)take((size_t)N_NODES * F_IN * 2);   // layer-1 A / layer-1 out (reused)
  f16*   H2h   = (f16*)take((size_t)N_NODES * HC * 2);     // layer-2 out
  f16*   WT    = (f16*)take((size_t)NW * F_IN * 2);        // fused transposed weights
  f16*   XL    = (f16*)take((size_t)N_NODES * HC * 2);
  f16*   XR    = (f16*)take((size_t)N_NODES * HC * 2);
  int*   counts= (int*)take((size_t)N_NODES * 4);
  int*   offs  = (int*)take((size_t)(N_NODES + 1) * 4);
  int*   cur   = (int*)take((size_t)N_NODES * 4);
  int2*  ecsr  = (int2*)take((size_t)N_EDGES * 8);

  hipMemsetAsync(counts, 0, N_NODES * 4, stream);
  count_edges<<<N_EDGES / 256, 256, 0, stream>>>(dst, counts);
  scan_offsets<<<1, 256, 0, stream>>>(counts, offs, cur);
  fill_csr<<<N_EDGES / 256, 256, 0, stream>>>(dst, src, eattr, cur, ecsr);

  cvt_f32_f16<<<(N_NODES * F_IN) / 1024, 256, 0, stream>>>(x, Xh, N_NODES * F_IN);

  // layer 1: Xh -> Xh (edge kernel writes after GEMM has consumed Xh; stream-ordered, safe)
  run_layer(Xh, Wl1, bl1, Wr1, br1, We1, att1, bias1,
            WT, XL, XR, offs, ecsr, Xh, stream);
  // layer 2: Xh -> H2h
  run_layer(Xh, Wl2, bl2, Wr2, br2, We2, att2, bias2,
            WT, XL, XR, offs, ecsr, H2h, stream);

  pool_kernel<<<dim3(NGRAPH, HC / 256), 256, 0, stream>>>(H2h, batch, out);
}

// Round 5
// 907.093 us; speedup vs baseline: 1.0328x; 1.0328x over previous
//
#include <hip/hip_runtime.h>

typedef unsigned short u16;
typedef _Float16 f16;
typedef _Float16 f16x8 __attribute__((ext_vector_type(8)));
typedef _Float16 f16x2 __attribute__((ext_vector_type(2)));
typedef float f32x4 __attribute__((ext_vector_type(4)));

#define AS1 __attribute__((address_space(1)))
#define AS3 __attribute__((address_space(3)))

constexpr int N_NODES = 8000;
constexpr int N_EDGES = 64000;
constexpr int F_IN    = 2560;   // in channels (== H*C, both layers)
constexpr int HEADS   = 8;
constexpr int CPH     = 320;    // channels per head
constexpr int HC      = 2560;   // HEADS*CPH
constexpr int NW      = 5120;   // fused GEMM output width (XL | XR)
constexpr int NGRAPH  = 16;
constexpr float SLOPE = 0.2f;

// ---------------- f32 -> f16 bulk convert (n divisible by 1024) ----------------
__global__ __launch_bounds__(256)
void cvt_f32_f16(const float* __restrict__ in, f16* __restrict__ out, int n)
{
  const int i = (blockIdx.x * 256 + threadIdx.x) * 4;
  if (i >= n) return;
  const float4 v = *(const float4*)(in + i);
  f16 o[4] = {(f16)v.x, (f16)v.y, (f16)v.z, (f16)v.w};
  *(ushort4*)(out + i) = *(const ushort4*)o;
}

// ------ weight transpose + convert: in f32 [R=2560][C=2560] -> out f16 [C][R] ------
__global__ __launch_bounds__(256)
void transpose_w(const float* __restrict__ in, f16* __restrict__ out)
{
  __shared__ u16 tile[64][66];     // +2 pad to break bank stride
  const int bx = blockIdx.x * 64;  // col tile (input)
  const int by = blockIdx.y * 64;  // row tile (input)
  const int tx = threadIdx.x & 63;
  const int ty = threadIdx.x >> 6;
  #pragma unroll
  for (int i = ty; i < 64; i += 4) {
    f16 h = (f16)in[(size_t)(by + i) * HC + bx + tx];
    u16 u; __builtin_memcpy(&u, &h, 2);
    tile[i][tx] = u;
  }
  __syncthreads();
  #pragma unroll
  for (int i = ty; i < 64; i += 4) {
    u16 u = tile[tx][i];
    f16 h; __builtin_memcpy(&h, &u, 2);
    out[(size_t)(bx + i) * F_IN + by + tx] = h;
  }
}

// ---- Fused GEMM: [XL|XR][M,5120](f16) = A[M,K](f16) @ BT[5120,K]^T + bias; fp32 acc ----
// 8-phase pipelined 256x256 tile, BK=64, 512 threads / 8 waves (2M x 4N),
// per-wave 128x64 output (8x4 16x16x32 fragments). 128 KiB LDS double buffer.
// Counted vmcnt(4) at phases 4/8 only; raw s_barrier; setprio around MFMA.
// Per-row XOR-8 16B-chunk swizzle on LDS (verified 0 bank conflicts).
// XCD-local 2D chunk grid map (FETCH 162 MB = ideal); LDS round-trip epilogue
// (WRITE 80 MB = ideal).
// ROUND-5 CHANGE vs R2: (a) removed all sched_barrier(0) order-pins -- rule-18
// does not apply (no inline-asm ds_reads); m141/m137 evidence says pinning is
// a 10-40% loss on this structure class and the compiler's own waitcnt
// scheduling is near-optimal; (b) stage DMA issued BEFORE the fragment
// ds_reads in each phase (issue-early). launch_bounds restored to (512,2) --
// (512,4) caps the unified VGPR+AGPR file at 128/wave < acc alone (R4 failure).
__global__ __launch_bounds__(512, 2)
void gemm_fused(const f16* __restrict__ A, const f16* __restrict__ BT,
                const float* __restrict__ bl, const float* __restrict__ br,
                f16* __restrict__ XL, f16* __restrict__ XR)
{
  __shared__ __align__(16) f16 sm[65536];   // 128 KiB
  f16* const sA0 = sm;
  f16* const sA1 = sm + 16384;
  f16* const sB0 = sm + 32768;
  f16* const sB1 = sm + 49152;

  const int t    = threadIdx.x;
  const int lane = t & 63;
  const int wave = t >> 6;

  // XCD-local 2D chunk: xcd = bid%8 owns m-tiles [4*xcd, 4*xcd+3] x n 0..19
  const int bid0 = (int)blockIdx.x;      // 640 = 32 m-tiles x 20 n-tiles
  const int xcd  = bid0 & 7;
  const int ic   = bid0 >> 3;            // 0..79, dispatch order within XCD
  const int m0   = (xcd * 4 + (ic & 3)) * 256;   // m-fastest: A panels L2-pinned
  const int n0   = (ic >> 2) * 256;

  const int fm = (wave >> 2) * 128;     // 0 / 128
  const int fn = (wave & 3) * 64;       // 0..192
  const int ml = lane & 15;
  const int lq = lane >> 4;

  auto stageA = [&](f16* D, int half, int kt) {
    const int k0 = kt * 64;
    #pragma unroll
    for (int jj = 0; jj < 2; ++jj) {
      const int s  = jj * 512 + t;
      const int r  = s >> 3;
      const int lc = (s & 7) ^ (r & 7);
      int gr = m0 + half * 128 + r;
      gr = (gr < N_NODES) ? gr : (N_NODES - 1);   // clamp pad rows (stores guarded)
      const f16* g = A + (size_t)gr * F_IN + k0 + lc * 8;
      __builtin_amdgcn_global_load_lds((AS1 const void*)g,
                                       (AS3 void*)(D + half * 8192 + s * 8), 16, 0, 0);
    }
  };
  auto stageB = [&](f16* D, int half, int kt) {
    const int k0 = kt * 64;
    #pragma unroll
    for (int jj = 0; jj < 2; ++jj) {
      const int s  = jj * 512 + t;
      const int r  = s >> 3;
      const int lc = (s & 7) ^ (r & 7);
      const f16* g = BT + (size_t)(n0 + half * 128 + r) * F_IN + k0 + lc * 8;
      __builtin_amdgcn_global_load_lds((AS1 const void*)g,
                                       (AS3 void*)(D + half * 8192 + s * 8), 16, 0, 0);
    }
  };
  auto ldA = [&](const f16* S, int i, int kk) -> f16x8 {
    const int row = fm + i * 16 + ml;
    const int p   = (kk * 4 + lq) ^ (row & 7);
    return *(const f16x8*)(S + row * 64 + p * 8);
  };
  auto ldB = [&](const f16* S, int j, int kk) -> f16x8 {
    const int row = fn + j * 16 + ml;
    const int p   = (kk * 4 + lq) ^ (row & 7);
    return *(const f16x8*)(S + row * 64 + p * 8);
  };

  f32x4 acc[8][4] = {};
  f16x8 bf[4][2];

#define MMROW(i, A0_, A1_)                                                                   \
    _Pragma("unroll")                                                                        \
    for (int j = 0; j < 4; ++j) {                                                            \
      acc[i][j] = __builtin_amdgcn_mfma_f32_16x16x32_f16(A0_, bf[j][0], acc[i][j], 0, 0, 0); \
      acc[i][j] = __builtin_amdgcn_mfma_f32_16x16x32_f16(A1_, bf[j][1], acc[i][j], 0, 0, 0); \
    }

#define PHASE(SA, q, STG)                          \
  {                                                \
    STG;                                           \
    const f16x8 p00 = ldA(SA, 2*(q),     0);       \
    const f16x8 p01 = ldA(SA, 2*(q),     1);       \
    const f16x8 p10 = ldA(SA, 2*(q) + 1, 0);       \
    const f16x8 p11 = ldA(SA, 2*(q) + 1, 1);       \
    __builtin_amdgcn_s_barrier();                  \
    __builtin_amdgcn_s_setprio(1);                 \
    MMROW(2*(q),     p00, p01)                     \
    MMROW(2*(q) + 1, p10, p11)                     \
    __builtin_amdgcn_s_setprio(0);                 \
  }

#define ENDPH() { __builtin_amdgcn_s_barrier(); }
#define LOADB(SB) { _Pragma("unroll") for (int j = 0; j < 4; ++j) { bf[j][0] = ldB(SB, j, 0); bf[j][1] = ldB(SB, j, 1); } }

  // prologue: tile0 A+B, tile1 B; 12 loads, wait oldest 8 (tile0 complete)
  stageA(sA0, 0, 0); stageA(sA0, 1, 0);
  stageB(sB0, 0, 0); stageB(sB0, 1, 0);
  stageB(sB1, 0, 1); stageB(sB1, 1, 1);
  asm volatile("s_waitcnt vmcnt(4)" ::: "memory");
  __builtin_amdgcn_s_barrier();

  for (int it = 0; it < 20; ++it) {        // 40 K-tiles, 2 per iteration
    const int T  = 2 * it;
    const int t1 = T + 1;                              // <= 39 always
    const int t2 = (T + 2 < 40) ? T + 2 : 39;          // clamp: uniform load counts,
    const int t3 = (T + 3 < 40) ? T + 3 : 39;          // dup stages land in dead bufs

    // ---- K-tile T from buf0 ----
    LOADB(sB0)
    PHASE(sA0, 0, stageA(sA1, 0, t1)) ENDPH()
    PHASE(sA0, 1, stageA(sA1, 1, t1)) ENDPH()
    PHASE(sA0, 2, stageB(sB0, 0, t2)) ENDPH()
    PHASE(sA0, 3, stageB(sB0, 1, t2))
    asm volatile("s_waitcnt vmcnt(4)" ::: "memory");
    ENDPH()
    // ---- K-tile T+1 from buf1 ----
    LOADB(sB1)
    PHASE(sA1, 0, stageA(sA0, 0, t2)) ENDPH()
    PHASE(sA1, 1, stageA(sA0, 1, t2)) ENDPH()
    PHASE(sA1, 2, stageB(sB1, 0, t3)) ENDPH()
    PHASE(sA1, 3, stageB(sB1, 1, t3))
    asm volatile("s_waitcnt vmcnt(4)" ::: "memory");
    ENDPH()
  }

#undef MMROW
#undef PHASE
#undef ENDPH
#undef LOADB

  // ---- epilogue: drain pending stages, then LDS round-trip for coalesced stores ----
  asm volatile("s_waitcnt vmcnt(0)" ::: "memory");
  __builtin_amdgcn_s_barrier();

  const bool left = (n0 < HC);
  f16* __restrict__ OUT = left ? XL : XR;
  const float* __restrict__ bias = left ? bl : br;
  const int nb = left ? n0 : (n0 - HC);
  const int rg = (lane >> 4) * 4;
  f16* const wbase = sm + wave * 8192;   // 16 KB per wave (128 rows x 64 cols)

  #pragma unroll
  for (int j = 0; j < 4; ++j) {
    const float bv = bias[nb + fn + j * 16 + ml];
    #pragma unroll
    for (int i = 0; i < 8; ++i) {
      #pragma unroll
      for (int r = 0; r < 4; ++r) {
        const int row = i * 16 + rg + r;
        const int col = j * 16 + ml;
        const int pc  = (col >> 3) ^ (row & 7);
        wbase[row * 64 + pc * 8 + (col & 7)] = (f16)(acc[i][j][r] + bv);
      }
    }
  }
  __syncthreads();
  #pragma unroll
  for (int it = 0; it < 16; ++it) {
    const int row = it * 8 + (lane >> 3);
    const int ch  = lane & 7;
    const int pc  = ch ^ (row & 7);
    const f16x8 v = *(const f16x8*)(wbase + row * 64 + pc * 8);
    const int gm = m0 + fm + row;
    if (gm < N_NODES)
      *(f16x8*)(OUT + (size_t)gm * HC + nb + fn + ch * 8) = v;
  }
}

// ---------------- CSR build ----------------
__global__ __launch_bounds__(256)
void count_edges(const int* __restrict__ dst, int* __restrict__ counts)
{
  const int e = blockIdx.x * 256 + threadIdx.x;
  if (e < N_EDGES) atomicAdd(&counts[dst[e]], 1);
}

__global__ __launch_bounds__(256)
void scan_offsets(const int* __restrict__ counts, int* __restrict__ offs, int* __restrict__ cur)
{
  __shared__ int wtot[4];
  const int t = threadIdx.x;
  const int lane = t & 63, wave = t >> 6;
  const int base = t * 32;
  int loc[32];
  int run = 0;
  #pragma unroll
  for (int i = 0; i < 32; ++i) {
    const int idx = base + i;
    const int v = (idx < N_NODES) ? counts[idx] : 0;
    loc[i] = run;
    run += v;
  }
  int incl = run;
  #pragma unroll
  for (int off = 1; off < 64; off <<= 1) {
    int y = __shfl_up(incl, off, 64);
    if (lane >= off) incl += y;
  }
  const int excl = incl - run;
  if (lane == 63) wtot[wave] = incl;
  __syncthreads();
  int wb = 0;
  for (int wv = 0; wv < wave; ++wv) wb += wtot[wv];
  const int mybase = wb + excl;
  #pragma unroll
  for (int i = 0; i < 32; ++i) {
    const int idx = base + i;
    if (idx < N_NODES) { offs[idx] = mybase + loc[i]; cur[idx] = mybase + loc[i]; }
  }
  if (t == 255) offs[N_NODES] = wb + incl;
}

// fill CSR with PACKED edge meta {src, eattr_bits}: one 8B load replaces the
// eids->src/eattr 3-load chain in the edge kernel.
__global__ __launch_bounds__(256)
void fill_csr(const int* __restrict__ dst, const int* __restrict__ srcv,
              const float* __restrict__ ea, int* __restrict__ cur,
              int2* __restrict__ ecsr)
{
  const int e = blockIdx.x * 256 + threadIdx.x;
  if (e < N_EDGES) {
    const int p = atomicAdd(&cur[dst[e]], 1);
    ecsr[p] = make_int2(srcv[e], __float_as_int(ea[e]));
  }
}

// ---- Fused edge phase: scores + online segment-softmax + aggregation, one pass ----
// R2 loop structure (best measured) + packed ecsr meta. Single-edge iteration,
// ping-pong prefetch: row of p+1 and meta of p+2 in flight during compute of p.
// Edge phase is line-service bound (~2 TB/s gather); keep it simple.
__global__ __launch_bounds__(256)
void gat_edge_fused(const f16* __restrict__ XL, const f16* __restrict__ XR,
                    const float* __restrict__ We, const float* __restrict__ att,
                    const int2* __restrict__ ecsr, const int* __restrict__ offs,
                    const float* __restrict__ bias,
                    f16* __restrict__ out)
{
  const int n    = blockIdx.x;
  const int t    = threadIdx.x;
  const int wave = t >> 6;
  const int lane = t & 63;
  const int half = lane >> 5;
  const int l32  = lane & 31;
  const int h    = wave * 2 + half;
  const int c8   = h * CPH + l32 * 8;        // 8 contiguous channels (16B aligned)
  const int c2   = h * CPH + 256 + l32 * 2;  // 2 contiguous channels (4B aligned)

  float xr[10], wv[10], av[10];
  {
    const f16x8 v8 = *(const f16x8*)(XR + (size_t)n * HC + c8);
    const f16x2 v2 = *(const f16x2*)(XR + (size_t)n * HC + c2);
    #pragma unroll
    for (int k = 0; k < 8; ++k) xr[k] = (float)v8[k];
    xr[8] = (float)v2[0]; xr[9] = (float)v2[1];
  }
  {
    const float4 w0 = *(const float4*)(We + c8);
    const float4 w1 = *(const float4*)(We + c8 + 4);
    const float4 a0 = *(const float4*)(att + c8);
    const float4 a1 = *(const float4*)(att + c8 + 4);
    wv[0]=w0.x; wv[1]=w0.y; wv[2]=w0.z; wv[3]=w0.w;
    wv[4]=w1.x; wv[5]=w1.y; wv[6]=w1.z; wv[7]=w1.w;
    av[0]=a0.x; av[1]=a0.y; av[2]=a0.z; av[3]=a0.w;
    av[4]=a1.x; av[5]=a1.y; av[6]=a1.z; av[7]=a1.w;
    wv[8] = We[c2]; wv[9] = We[c2 + 1];
    av[8] = att[c2]; av[9] = att[c2 + 1];
  }

  float m = -3.0e38f, l = 0.f;
  float acc[10];
  #pragma unroll
  for (int k = 0; k < 10; ++k) acc[k] = 0.f;

  const int b = offs[n], e = offs[n + 1];
  if (b < e) {
    int2 mA = ecsr[b];
    f16x8 v8A = *(const f16x8*)(XL + (size_t)mA.x * HC + c8);
    f16x2 v2A = *(const f16x2*)(XL + (size_t)mA.x * HC + c2);
    int2 mB = (b + 1 < e) ? ecsr[b + 1] : make_int2(mA.x, 0);

    for (int p = b; p < e; ++p) {
      // prefetch row of p+1 (mB.x valid even past end -> harmless load)
      const f16* rowN = XL + (size_t)mB.x * HC;
      const f16x8 v8N = *(const f16x8*)(rowN + c8);
      const f16x2 v2N = *(const f16x2*)(rowN + c2);
      // prefetch meta of p+2 (clamped -> branch-free)
      const int pn = (p + 2 < e) ? (p + 2) : (e - 1);
      const int2 mC = ecsr[pn];

      // process edge p
      const float ea = __int_as_float(mA.y);
      float xl[10];
      #pragma unroll
      for (int k = 0; k < 8; ++k) xl[k] = (float)v8A[k];
      xl[8] = (float)v2A[0]; xl[9] = (float)v2A[1];
      float partial = 0.f;
      #pragma unroll
      for (int k = 0; k < 10; ++k) {
        float v = xl[k] + xr[k] + ea * wv[k];
        v = (v > 0.f) ? v : SLOPE * v;
        partial += v * av[k];
      }
      #pragma unroll
      for (int msk = 16; msk >= 1; msk >>= 1)
        partial += __shfl_xor(partial, msk, 64);
      const float sc    = partial;
      const float mn    = fmaxf(m, sc);
      const float scale = __expf(m - mn);
      const float w     = __expf(sc - mn);
      l = l * scale + w;
      #pragma unroll
      for (int k = 0; k < 10; ++k) acc[k] = acc[k] * scale + w * xl[k];
      m = mn;

      // shift pipeline
      mA = mB; v8A = v8N; v2A = v2N; mB = mC;
    }
  }

  const float inv = (l > 0.f) ? 1.f / l : 0.f;   // deg-0 node -> out = bias (matches ref)
  f16x8 s8;
  #pragma unroll
  for (int k = 0; k < 8; ++k) s8[k] = (f16)(acc[k] * inv + bias[c8 + k]);
  f16x2 s2;
  s2[0] = (f16)(acc[8] * inv + bias[c2]);
  s2[1] = (f16)(acc[9] * inv + bias[c2 + 1]);
  *(f16x8*)(out + (size_t)n * HC + c8) = s8;
  *(f16x2*)(out + (size_t)n * HC + c2) = s2;
}

// ---------------- global mean pool (batch is sorted), f16 in, f32 out ----------------
__global__ __launch_bounds__(256)
void pool_kernel(const f16* __restrict__ Hm, const int* __restrict__ batch, float* __restrict__ out)
{
  __shared__ int se[2];
  const int g = blockIdx.x;
  const int chunk = blockIdx.y;
  const int t = threadIdx.x;
  if (t < 2) {
    const int target = g + t;
    int lo = 0, hi = N_NODES;
    while (lo < hi) { const int mid = (lo + hi) >> 1; if (batch[mid] < target) lo = mid + 1; else hi = mid; }
    se[t] = lo;
  }
  __syncthreads();
  const int s0 = se[0], s1 = se[1];
  const int c = chunk * 256 + t;
  float sum = 0.f;
  for (int n = s0; n < s1; ++n) sum += (float)Hm[(size_t)n * HC + c];
  int cnt = s1 - s0; if (cnt < 1) cnt = 1;
  out[g * HC + c] = sum / (float)cnt;
}

// ---------------- host: one GATv2 layer (A f16 -> OUT f16) ----------------
static void run_layer(const f16* A, const float* Wl, const float* bl,
                      const float* Wr, const float* br,
                      const float* We, const float* att, const float* bias,
                      f16* WT, f16* XL, f16* XR,
                      const int* offs, const int2* ecsr, f16* OUT, hipStream_t stream)
{
  dim3 tgrid(HC / 64, F_IN / 64);
  transpose_w<<<tgrid, 256, 0, stream>>>(Wl, WT);
  transpose_w<<<tgrid, 256, 0, stream>>>(Wr, WT + (size_t)HC * F_IN);
  gemm_fused<<<32 * (NW / 256), 512, 0, stream>>>(A, WT, bl, br, XL, XR);
  gat_edge_fused<<<N_NODES, 256, 0, stream>>>(XL, XR, We, att, ecsr, offs, bias, OUT);
}

extern "C" void kernel_launch(void* const* d_in, const int* in_sizes, int n_in,
                              void* d_out, int out_size, void* d_ws, size_t ws_size,
                              hipStream_t stream)
{
  const float* x     = (const float*)d_in[0];
  const int*   eidx  = (const int*)d_in[1];
  const float* eattr = (const float*)d_in[2];
  const int*   batch = (const int*)d_in[3];
  const float* Wl1  = (const float*)d_in[4];
  const float* bl1  = (const float*)d_in[5];
  const float* Wr1  = (const float*)d_in[6];
  const float* br1  = (const float*)d_in[7];
  const float* We1  = (const float*)d_in[8];
  const float* att1 = (const float*)d_in[9];
  const float* bias1= (const float*)d_in[10];
  const float* Wl2  = (const float*)d_in[11];
  const float* bl2  = (const float*)d_in[12];
  const float* Wr2  = (const float*)d_in[13];
  const float* br2  = (const float*)d_in[14];
  const float* We2  = (const float*)d_in[15];
  const float* att2 = (const float*)d_in[16];
  const float* bias2= (const float*)d_in[17];
  float* out = (float*)d_out;

  const int* src = eidx;
  const int* dst = eidx + N_EDGES;

  char* w = (char*)d_ws;
  auto take = [&](size_t b) { char* p = w; w += (b + 255) & ~(size_t)255; return p; };
  f16*   Xh    = (f16*)take((size_t)N_NODES * F_IN * 2);   // layer-1 A / layer-1 out (reused)
  f16*   H2h   = (f16*)take((size_t)N_NODES * HC * 2);     // layer-2 out
  f16*   WT    = (f16*)take((size_t)NW * F_IN * 2);        // fused transposed weights
  f16*   XL    = (f16*)take((size_t)N_NODES * HC * 2);
  f16*   XR    = (f16*)take((size_t)N_NODES * HC * 2);
  int*   counts= (int*)take((size_t)N_NODES * 4);
  int*   offs  = (int*)take((size_t)(N_NODES + 1) * 4);
  int*   cur   = (int*)take((size_t)N_NODES * 4);
  int2*  ecsr  = (int2*)take((size_t)N_EDGES * 8);

  hipMemsetAsync(counts, 0, N_NODES * 4, stream);
  count_edges<<<N_EDGES / 256, 256, 0, stream>>>(dst, counts);
  scan_offsets<<<1, 256, 0, stream>>>(counts, offs, cur);
  fill_csr<<<N_EDGES / 256, 256, 0, stream>>>(dst, src, eattr, cur, ecsr);

  cvt_f32_f16<<<(N_NODES * F_IN) / 1024, 256, 0, stream>>>(x, Xh, N_NODES * F_IN);

  // layer 1: Xh -> Xh (edge kernel writes after GEMM has consumed Xh; stream-ordered, safe)
  run_layer(Xh, Wl1, bl1, Wr1, br1, We1, att1, bias1,
            WT, XL, XR, offs, ecsr, Xh, stream);
  // layer 2: Xh -> H2h
  run_layer(Xh, Wl2, bl2, Wr2, br2, We2, att2, bias2,
            WT, XL, XR, offs, ecsr, H2h, stream);

  pool_kernel<<<dim3(NGRAPH, HC / 256), 256, 0, stream>>>(H2h, batch, out);
}

// Round 6
// 883.138 us; speedup vs baseline: 1.0608x; 1.0271x over previous
//
#include <hip/hip_runtime.h>

typedef unsigned short u16;
typedef _Float16 f16;
typedef _Float16 f16x8 __attribute__((ext_vector_type(8)));
typedef _Float16 f16x2 __attribute__((ext_vector_type(2)));
typedef float f32x4 __attribute__((ext_vector_type(4)));

#define AS1 __attribute__((address_space(1)))
#define AS3 __attribute__((address_space(3)))

constexpr int N_NODES = 8000;
constexpr int N_EDGES = 64000;
constexpr int F_IN    = 2560;   // in channels (== H*C, both layers)
constexpr int HEADS   = 8;
constexpr int CPH     = 320;    // channels per head
constexpr int HC      = 2560;   // HEADS*CPH
constexpr int NW      = 5120;   // fused GEMM output width (XL | XR)
constexpr int NGRAPH  = 16;
constexpr float SLOPE = 0.2f;

// ---------------- f32 -> f16 bulk convert (n divisible by 1024) ----------------
__global__ __launch_bounds__(256)
void cvt_f32_f16(const float* __restrict__ in, f16* __restrict__ out, int n)
{
  const int i = (blockIdx.x * 256 + threadIdx.x) * 4;
  if (i >= n) return;
  const float4 v = *(const float4*)(in + i);
  f16 o[4] = {(f16)v.x, (f16)v.y, (f16)v.z, (f16)v.w};
  *(ushort4*)(out + i) = *(const ushort4*)o;
}

// ------ weight transpose + convert: in f32 [R=2560][C=2560] -> out f16 [C][R] ------
__global__ __launch_bounds__(256)
void transpose_w(const float* __restrict__ in, f16* __restrict__ out)
{
  __shared__ u16 tile[64][66];     // +2 pad to break bank stride
  const int bx = blockIdx.x * 64;  // col tile (input)
  const int by = blockIdx.y * 64;  // row tile (input)
  const int tx = threadIdx.x & 63;
  const int ty = threadIdx.x >> 6;
  #pragma unroll
  for (int i = ty; i < 64; i += 4) {
    f16 h = (f16)in[(size_t)(by + i) * HC + bx + tx];
    u16 u; __builtin_memcpy(&u, &h, 2);
    tile[i][tx] = u;
  }
  __syncthreads();
  #pragma unroll
  for (int i = ty; i < 64; i += 4) {
    u16 u = tile[tx][i];
    f16 h; __builtin_memcpy(&h, &u, 2);
    out[(size_t)(bx + i) * F_IN + by + tx] = h;
  }
}

// ---- Fused GEMM: [XL|XR][M,5120](f16) = A[M,K](f16) @ BT[5120,K]^T + bias; fp32 acc ----
// 256x256 tile, BK=64, 512 threads / 8 waves (2M x 4N), per-wave 128x64 output.
// 128 KiB LDS double buffer; per-row XOR-8 16B-chunk swizzle (0 bank conflicts);
// XCD-local 2D chunk grid map (FETCH 162 MB = ideal); LDS round-trip epilogue
// (WRITE 80 MB = ideal).
//
// ROUND-6 CHANGE: FREE-RUNNING K-TILES. R2-R5 held ~1330 cy/phase vs 620 cy of
// MFMA work: the per-phase barrier lockstep serialized every wave's ds_read
// window against its MFMA window with no co-scheduled wave to fill either pipe
// (m114 overlap forbidden by lockstep). Race analysis: within a K-tile all
// ds_reads hit the current buffer half, all stage-DMA targets the dead half ->
// interior barriers are not needed for correctness. Now: ONE vmcnt(0)+s_barrier
// per K-tile boundary, zero interior barriers; waves drift out of phase so one
// wave's LDS/stage work runs under another's MFMA. Per-wave issue order stays
// phase-shaped via sched_barrier(0) after each MFMA cluster (measured neutral,
// bounds register liveness). The boundary vmcnt asm's "memory" clobber blocks
// ds_read hoisting above the drain (rule-18-safe). Stages front-loaded
// (A before q0 MFMA, B before q1) -> youngest load has ~2.5 phases of lead.
__global__ __launch_bounds__(512, 2)
void gemm_fused(const f16* __restrict__ A, const f16* __restrict__ BT,
                const float* __restrict__ bl, const float* __restrict__ br,
                f16* __restrict__ XL, f16* __restrict__ XR)
{
  __shared__ __align__(16) f16 sm[65536];   // 128 KiB
  f16* const sA0 = sm;
  f16* const sA1 = sm + 16384;
  f16* const sB0 = sm + 32768;
  f16* const sB1 = sm + 49152;

  const int t    = threadIdx.x;
  const int lane = t & 63;
  const int wave = t >> 6;

  // XCD-local 2D chunk: xcd = bid%8 owns m-tiles [4*xcd, 4*xcd+3] x n 0..19
  const int bid0 = (int)blockIdx.x;      // 640 = 32 m-tiles x 20 n-tiles
  const int xcd  = bid0 & 7;
  const int ic   = bid0 >> 3;            // 0..79, dispatch order within XCD
  const int m0   = (xcd * 4 + (ic & 3)) * 256;   // m-fastest: A panels L2-pinned
  const int n0   = (ic >> 2) * 256;

  const int fm = (wave >> 2) * 128;     // 0 / 128
  const int fn = (wave & 3) * 64;       // 0..192
  const int ml = lane & 15;
  const int lq = lane >> 4;

  auto stageA = [&](f16* D, int half, int kt) {
    const int k0 = kt * 64;
    #pragma unroll
    for (int jj = 0; jj < 2; ++jj) {
      const int s  = jj * 512 + t;
      const int r  = s >> 3;
      const int lc = (s & 7) ^ (r & 7);
      int gr = m0 + half * 128 + r;
      gr = (gr < N_NODES) ? gr : (N_NODES - 1);   // clamp pad rows (stores guarded)
      const f16* g = A + (size_t)gr * F_IN + k0 + lc * 8;
      __builtin_amdgcn_global_load_lds((AS1 const void*)g,
                                       (AS3 void*)(D + half * 8192 + s * 8), 16, 0, 0);
    }
  };
  auto stageB = [&](f16* D, int half, int kt) {
    const int k0 = kt * 64;
    #pragma unroll
    for (int jj = 0; jj < 2; ++jj) {
      const int s  = jj * 512 + t;
      const int r  = s >> 3;
      const int lc = (s & 7) ^ (r & 7);
      const f16* g = BT + (size_t)(n0 + half * 128 + r) * F_IN + k0 + lc * 8;
      __builtin_amdgcn_global_load_lds((AS1 const void*)g,
                                       (AS3 void*)(D + half * 8192 + s * 8), 16, 0, 0);
    }
  };
  auto ldA = [&](const f16* S, int i, int kk) -> f16x8 {
    const int row = fm + i * 16 + ml;
    const int p   = (kk * 4 + lq) ^ (row & 7);
    return *(const f16x8*)(S + row * 64 + p * 8);
  };
  auto ldB = [&](const f16* S, int j, int kk) -> f16x8 {
    const int row = fn + j * 16 + ml;
    const int p   = (kk * 4 + lq) ^ (row & 7);
    return *(const f16x8*)(S + row * 64 + p * 8);
  };

  f32x4 acc[8][4] = {};
  f16x8 bf[4][2];

#define MMROW(i, A0_, A1_)                                                                   \
    _Pragma("unroll")                                                                        \
    for (int j = 0; j < 4; ++j) {                                                            \
      acc[i][j] = __builtin_amdgcn_mfma_f32_16x16x32_f16(A0_, bf[j][0], acc[i][j], 0, 0, 0); \
      acc[i][j] = __builtin_amdgcn_mfma_f32_16x16x32_f16(A1_, bf[j][1], acc[i][j], 0, 0, 0); \
    }

#define SBAR0() __builtin_amdgcn_sched_barrier(0)
#define LOADB(SB) { _Pragma("unroll") for (int j = 0; j < 4; ++j) { bf[j][0] = ldB(SB, j, 0); bf[j][1] = ldB(SB, j, 1); } }

  // prologue: stage tile 0 into buf0, drain, barrier
  stageA(sA0, 0, 0); stageA(sA0, 1, 0);
  stageB(sB0, 0, 0); stageB(sB0, 1, 0);
  asm volatile("s_waitcnt vmcnt(0)" ::: "memory");
  __builtin_amdgcn_s_barrier();
  SBAR0();

  for (int T = 0; T < 40; ++T) {
    f16* const rA = (T & 1) ? sA1 : sA0;
    f16* const rB = (T & 1) ? sB1 : sB0;
    f16* const wA = (T & 1) ? sA0 : sA1;
    f16* const wB = (T & 1) ? sB0 : sB1;
    const int Tn = (T + 1 < 40) ? (T + 1) : 39;   // tail: dup stage into dead buf

    LOADB(rB)
    // q0: rows fm+0..31
    {
      const f16x8 a00 = ldA(rA, 0, 0), a01 = ldA(rA, 0, 1);
      const f16x8 a10 = ldA(rA, 1, 0), a11 = ldA(rA, 1, 1);
      stageA(wA, 0, Tn); stageA(wA, 1, Tn);
      __builtin_amdgcn_s_setprio(1);
      MMROW(0, a00, a01)
      MMROW(1, a10, a11)
      __builtin_amdgcn_s_setprio(0);
    }
    SBAR0();
    // q1: rows fm+32..63
    {
      const f16x8 a00 = ldA(rA, 2, 0), a01 = ldA(rA, 2, 1);
      const f16x8 a10 = ldA(rA, 3, 0), a11 = ldA(rA, 3, 1);
      stageB(wB, 0, Tn); stageB(wB, 1, Tn);
      __builtin_amdgcn_s_setprio(1);
      MMROW(2, a00, a01)
      MMROW(3, a10, a11)
      __builtin_amdgcn_s_setprio(0);
    }
    SBAR0();
    // q2: rows fm+64..95
    {
      const f16x8 a00 = ldA(rA, 4, 0), a01 = ldA(rA, 4, 1);
      const f16x8 a10 = ldA(rA, 5, 0), a11 = ldA(rA, 5, 1);
      __builtin_amdgcn_s_setprio(1);
      MMROW(4, a00, a01)
      MMROW(5, a10, a11)
      __builtin_amdgcn_s_setprio(0);
    }
    SBAR0();
    // q3: rows fm+96..127
    {
      const f16x8 a00 = ldA(rA, 6, 0), a01 = ldA(rA, 6, 1);
      const f16x8 a10 = ldA(rA, 7, 0), a11 = ldA(rA, 7, 1);
      __builtin_amdgcn_s_setprio(1);
      MMROW(6, a00, a01)
      MMROW(7, a10, a11)
      __builtin_amdgcn_s_setprio(0);
    }
    // K-tile boundary: drain all stage-DMA ("memory" clobber also fences the
    // compiler: no ds_read of the next tile can hoist above this), then sync.
    asm volatile("s_waitcnt vmcnt(0)" ::: "memory");
    __builtin_amdgcn_s_barrier();
    SBAR0();
  }

#undef MMROW
#undef SBAR0
#undef LOADB

  // ---- epilogue: LDS round-trip for coalesced stores (DMA already drained) ----
  __syncthreads();

  const bool left = (n0 < HC);
  f16* __restrict__ OUT = left ? XL : XR;
  const float* __restrict__ bias = left ? bl : br;
  const int nb = left ? n0 : (n0 - HC);
  const int rg = (lane >> 4) * 4;
  f16* const wbase = sm + wave * 8192;   // 16 KB per wave (128 rows x 64 cols)

  #pragma unroll
  for (int j = 0; j < 4; ++j) {
    const float bv = bias[nb + fn + j * 16 + ml];
    #pragma unroll
    for (int i = 0; i < 8; ++i) {
      #pragma unroll
      for (int r = 0; r < 4; ++r) {
        const int row = i * 16 + rg + r;
        const int col = j * 16 + ml;
        const int pc  = (col >> 3) ^ (row & 7);
        wbase[row * 64 + pc * 8 + (col & 7)] = (f16)(acc[i][j][r] + bv);
      }
    }
  }
  __syncthreads();
  #pragma unroll
  for (int it = 0; it < 16; ++it) {
    const int row = it * 8 + (lane >> 3);
    const int ch  = lane & 7;
    const int pc  = ch ^ (row & 7);
    const f16x8 v = *(const f16x8*)(wbase + row * 64 + pc * 8);
    const int gm = m0 + fm + row;
    if (gm < N_NODES)
      *(f16x8*)(OUT + (size_t)gm * HC + nb + fn + ch * 8) = v;
  }
}

// ---------------- CSR build ----------------
__global__ __launch_bounds__(256)
void count_edges(const int* __restrict__ dst, int* __restrict__ counts)
{
  const int e = blockIdx.x * 256 + threadIdx.x;
  if (e < N_EDGES) atomicAdd(&counts[dst[e]], 1);
}

__global__ __launch_bounds__(256)
void scan_offsets(const int* __restrict__ counts, int* __restrict__ offs, int* __restrict__ cur)
{
  __shared__ int wtot[4];
  const int t = threadIdx.x;
  const int lane = t & 63, wave = t >> 6;
  const int base = t * 32;
  int loc[32];
  int run = 0;
  #pragma unroll
  for (int i = 0; i < 32; ++i) {
    const int idx = base + i;
    const int v = (idx < N_NODES) ? counts[idx] : 0;
    loc[i] = run;
    run += v;
  }
  int incl = run;
  #pragma unroll
  for (int off = 1; off < 64; off <<= 1) {
    int y = __shfl_up(incl, off, 64);
    if (lane >= off) incl += y;
  }
  const int excl = incl - run;
  if (lane == 63) wtot[wave] = incl;
  __syncthreads();
  int wb = 0;
  for (int wv = 0; wv < wave; ++wv) wb += wtot[wv];
  const int mybase = wb + excl;
  #pragma unroll
  for (int i = 0; i < 32; ++i) {
    const int idx = base + i;
    if (idx < N_NODES) { offs[idx] = mybase + loc[i]; cur[idx] = mybase + loc[i]; }
  }
  if (t == 255) offs[N_NODES] = wb + incl;
}

// fill CSR with PACKED edge meta {src, eattr_bits}: one 8B load replaces the
// eids->src/eattr 3-load chain in the edge kernel.
__global__ __launch_bounds__(256)
void fill_csr(const int* __restrict__ dst, const int* __restrict__ srcv,
              const float* __restrict__ ea, int* __restrict__ cur,
              int2* __restrict__ ecsr)
{
  const int e = blockIdx.x * 256 + threadIdx.x;
  if (e < N_EDGES) {
    const int p = atomicAdd(&cur[dst[e]], 1);
    ecsr[p] = make_int2(srcv[e], __float_as_int(ea[e]));
  }
}

// ---- Fused edge phase: scores + online segment-softmax + aggregation, one pass ----
// R2 loop structure (best measured across 4 variants; gather-service bound) +
// packed ecsr meta. Single-edge iteration, ping-pong prefetch.
__global__ __launch_bounds__(256)
void gat_edge_fused(const f16* __restrict__ XL, const f16* __restrict__ XR,
                    const float* __restrict__ We, const float* __restrict__ att,
                    const int2* __restrict__ ecsr, const int* __restrict__ offs,
                    const float* __restrict__ bias,
                    f16* __restrict__ out)
{
  const int n    = blockIdx.x;
  const int t    = threadIdx.x;
  const int wave = t >> 6;
  const int lane = t & 63;
  const int half = lane >> 5;
  const int l32  = lane & 31;
  const int h    = wave * 2 + half;
  const int c8   = h * CPH + l32 * 8;        // 8 contiguous channels (16B aligned)
  const int c2   = h * CPH + 256 + l32 * 2;  // 2 contiguous channels (4B aligned)

  float xr[10], wv[10], av[10];
  {
    const f16x8 v8 = *(const f16x8*)(XR + (size_t)n * HC + c8);
    const f16x2 v2 = *(const f16x2*)(XR + (size_t)n * HC + c2);
    #pragma unroll
    for (int k = 0; k < 8; ++k) xr[k] = (float)v8[k];
    xr[8] = (float)v2[0]; xr[9] = (float)v2[1];
  }
  {
    const float4 w0 = *(const float4*)(We + c8);
    const float4 w1 = *(const float4*)(We + c8 + 4);
    const float4 a0 = *(const float4*)(att + c8);
    const float4 a1 = *(const float4*)(att + c8 + 4);
    wv[0]=w0.x; wv[1]=w0.y; wv[2]=w0.z; wv[3]=w0.w;
    wv[4]=w1.x; wv[5]=w1.y; wv[6]=w1.z; wv[7]=w1.w;
    av[0]=a0.x; av[1]=a0.y; av[2]=a0.z; av[3]=a0.w;
    av[4]=a1.x; av[5]=a1.y; av[6]=a1.z; av[7]=a1.w;
    wv[8] = We[c2]; wv[9] = We[c2 + 1];
    av[8] = att[c2]; av[9] = att[c2 + 1];
  }

  float m = -3.0e38f, l = 0.f;
  float acc[10];
  #pragma unroll
  for (int k = 0; k < 10; ++k) acc[k] = 0.f;

  const int b = offs[n], e = offs[n + 1];
  if (b < e) {
    int2 mA = ecsr[b];
    f16x8 v8A = *(const f16x8*)(XL + (size_t)mA.x * HC + c8);
    f16x2 v2A = *(const f16x2*)(XL + (size_t)mA.x * HC + c2);
    int2 mB = (b + 1 < e) ? ecsr[b + 1] : make_int2(mA.x, 0);

    for (int p = b; p < e; ++p) {
      // prefetch row of p+1 (mB.x valid even past end -> harmless load)
      const f16* rowN = XL + (size_t)mB.x * HC;
      const f16x8 v8N = *(const f16x8*)(rowN + c8);
      const f16x2 v2N = *(const f16x2*)(rowN + c2);
      // prefetch meta of p+2 (clamped -> branch-free)
      const int pn = (p + 2 < e) ? (p + 2) : (e - 1);
      const int2 mC = ecsr[pn];

      // process edge p
      const float ea = __int_as_float(mA.y);
      float xl[10];
      #pragma unroll
      for (int k = 0; k < 8; ++k) xl[k] = (float)v8A[k];
      xl[8] = (float)v2A[0]; xl[9] = (float)v2A[1];
      float partial = 0.f;
      #pragma unroll
      for (int k = 0; k < 10; ++k) {
        float v = xl[k] + xr[k] + ea * wv[k];
        v = (v > 0.f) ? v : SLOPE * v;
        partial += v * av[k];
      }
      #pragma unroll
      for (int msk = 16; msk >= 1; msk >>= 1)
        partial += __shfl_xor(partial, msk, 64);
      const float sc    = partial;
      const float mn    = fmaxf(m, sc);
      const float scale = __expf(m - mn);
      const float w     = __expf(sc - mn);
      l = l * scale + w;
      #pragma unroll
      for (int k = 0; k < 10; ++k) acc[k] = acc[k] * scale + w * xl[k];
      m = mn;

      // shift pipeline
      mA = mB; v8A = v8N; v2A = v2N; mB = mC;
    }
  }

  const float inv = (l > 0.f) ? 1.f / l : 0.f;   // deg-0 node -> out = bias (matches ref)
  f16x8 s8;
  #pragma unroll
  for (int k = 0; k < 8; ++k) s8[k] = (f16)(acc[k] * inv + bias[c8 + k]);
  f16x2 s2;
  s2[0] = (f16)(acc[8] * inv + bias[c2]);
  s2[1] = (f16)(acc[9] * inv + bias[c2 + 1]);
  *(f16x8*)(out + (size_t)n * HC + c8) = s8;
  *(f16x2*)(out + (size_t)n * HC + c2) = s2;
}

// ---------------- global mean pool (batch is sorted), f16 in, f32 out ----------------
__global__ __launch_bounds__(256)
void pool_kernel(const f16* __restrict__ Hm, const int* __restrict__ batch, float* __restrict__ out)
{
  __shared__ int se[2];
  const int g = blockIdx.x;
  const int chunk = blockIdx.y;
  const int t = threadIdx.x;
  if (t < 2) {
    const int target = g + t;
    int lo = 0, hi = N_NODES;
    while (lo < hi) { const int mid = (lo + hi) >> 1; if (batch[mid] < target) lo = mid + 1; else hi = mid; }
    se[t] = lo;
  }
  __syncthreads();
  const int s0 = se[0], s1 = se[1];
  const int c = chunk * 256 + t;
  float sum = 0.f;
  for (int n = s0; n < s1; ++n) sum += (float)Hm[(size_t)n * HC + c];
  int cnt = s1 - s0; if (cnt < 1) cnt = 1;
  out[g * HC + c] = sum / (float)cnt;
}

// ---------------- host: one GATv2 layer (A f16 -> OUT f16) ----------------
static void run_layer(const f16* A, const float* Wl, const float* bl,
                      const float* Wr, const float* br,
                      const float* We, const float* att, const float* bias,
                      f16* WT, f16* XL, f16* XR,
                      const int* offs, const int2* ecsr, f16* OUT, hipStream_t stream)
{
  dim3 tgrid(HC / 64, F_IN / 64);
  transpose_w<<<tgrid, 256, 0, stream>>>(Wl, WT);
  transpose_w<<<tgrid, 256, 0, stream>>>(Wr, WT + (size_t)HC * F_IN);
  gemm_fused<<<32 * (NW / 256), 512, 0, stream>>>(A, WT, bl, br, XL, XR);
  gat_edge_fused<<<N_NODES, 256, 0, stream>>>(XL, XR, We, att, ecsr, offs, bias, OUT);
}

extern "C" void kernel_launch(void* const* d_in, const int* in_sizes, int n_in,
                              void* d_out, int out_size, void* d_ws, size_t ws_size,
                              hipStream_t stream)
{
  const float* x     = (const float*)d_in[0];
  const int*   eidx  = (const int*)d_in[1];
  const float* eattr = (const float*)d_in[2];
  const int*   batch = (const int*)d_in[3];
  const float* Wl1  = (const float*)d_in[4];
  const float* bl1  = (const float*)d_in[5];
  const float* Wr1  = (const float*)d_in[6];
  const float* br1  = (const float*)d_in[7];
  const float* We1  = (const float*)d_in[8];
  const float* att1 = (const float*)d_in[9];
  const float* bias1= (const float*)d_in[10];
  const float* Wl2  = (const float*)d_in[11];
  const float* bl2  = (const float*)d_in[12];
  const float* Wr2  = (const float*)d_in[13];
  const float* br2  = (const float*)d_in[14];
  const float* We2  = (const float*)d_in[15];
  const float* att2 = (const float*)d_in[16];
  const float* bias2= (const float*)d_in[17];
  float* out = (float*)d_out;

  const int* src = eidx;
  const int* dst = eidx + N_EDGES;

  char* w = (char*)d_ws;
  auto take = [&](size_t b) { char* p = w; w += (b + 255) & ~(size_t)255; return p; };
  f16*   Xh    = (f16*)take((size_t)N_NODES * F_IN * 2);   // layer-1 A / layer-1 out (reused)
  f16*   H2h   = (f16*)take((size_t)N_NODES * HC * 2);     // layer-2 out
  f16*   WT    = (f16*)take((size_t)NW * F_IN * 2);        // fused transposed weights
  f16*   XL    = (f16*)take((size_t)N_NODES * HC * 2);
  f16*   XR    = (f16*)take((size_t)N_NODES * HC * 2);
  int*   counts= (int*)take((size_t)N_NODES * 4);
  int*   offs  = (int*)take((size_t)(N_NODES + 1) * 4);
  int*   cur   = (int*)take((size_t)N_NODES * 4);
  int2*  ecsr  = (int2*)take((size_t)N_EDGES * 8);

  hipMemsetAsync(counts, 0, N_NODES * 4, stream);
  count_edges<<<N_EDGES / 256, 256, 0, stream>>>(dst, counts);
  scan_offsets<<<1, 256, 0, stream>>>(counts, offs, cur);
  fill_csr<<<N_EDGES / 256, 256, 0, stream>>>(dst, src, eattr, cur, ecsr);

  cvt_f32_f16<<<(N_NODES * F_IN) / 1024, 256, 0, stream>>>(x, Xh, N_NODES * F_IN);

  // layer 1: Xh -> Xh (edge kernel writes after GEMM has consumed Xh; stream-ordered, safe)
  run_layer(Xh, Wl1, bl1, Wr1, br1, We1, att1, bias1,
            WT, XL, XR, offs, ecsr, Xh, stream);
  // layer 2: Xh -> H2h
  run_layer(Xh, Wl2, bl2, Wr2, br2, We2, att2, bias2,
            WT, XL, XR, offs, ecsr, H2h, stream);

  pool_kernel<<<dim3(NGRAPH, HC / 256), 256, 0, stream>>>(H2h, batch, out);
}

// Round 7
// 879.099 us; speedup vs baseline: 1.0657x; 1.0046x over previous
//
#include <hip/hip_runtime.h>

typedef unsigned short u16;
typedef _Float16 f16;
typedef _Float16 f16x8 __attribute__((ext_vector_type(8)));
typedef _Float16 f16x2 __attribute__((ext_vector_type(2)));
typedef float f32x4 __attribute__((ext_vector_type(4)));

#define AS1 __attribute__((address_space(1)))
#define AS3 __attribute__((address_space(3)))

constexpr int N_NODES = 8000;
constexpr int N_EDGES = 64000;
constexpr int F_IN    = 2560;   // in channels (== H*C, both layers)
constexpr int HEADS   = 8;
constexpr int CPH     = 320;    // channels per head
constexpr int HC      = 2560;   // HEADS*CPH
constexpr int NW      = 5120;   // fused GEMM output width (XL | XR)
constexpr int NGRAPH  = 16;
constexpr float SLOPE = 0.2f;

// ---------------- f32 -> f16 bulk convert (n divisible by 1024) ----------------
__global__ __launch_bounds__(256)
void cvt_f32_f16(const float* __restrict__ in, f16* __restrict__ out, int n)
{
  const int i = (blockIdx.x * 256 + threadIdx.x) * 4;
  if (i >= n) return;
  const float4 v = *(const float4*)(in + i);
  f16 o[4] = {(f16)v.x, (f16)v.y, (f16)v.z, (f16)v.w};
  *(ushort4*)(out + i) = *(const ushort4*)o;
}

// ------ weight transpose + convert: in f32 [R=2560][C=2560] -> out f16 [C][R] ------
__global__ __launch_bounds__(256)
void transpose_w(const float* __restrict__ in, f16* __restrict__ out)
{
  __shared__ u16 tile[64][66];     // +2 pad to break bank stride
  const int bx = blockIdx.x * 64;  // col tile (input)
  const int by = blockIdx.y * 64;  // row tile (input)
  const int tx = threadIdx.x & 63;
  const int ty = threadIdx.x >> 6;
  #pragma unroll
  for (int i = ty; i < 64; i += 4) {
    f16 h = (f16)in[(size_t)(by + i) * HC + bx + tx];
    u16 u; __builtin_memcpy(&u, &h, 2);
    tile[i][tx] = u;
  }
  __syncthreads();
  #pragma unroll
  for (int i = ty; i < 64; i += 4) {
    u16 u = tile[tx][i];
    f16 h; __builtin_memcpy(&h, &u, 2);
    out[(size_t)(bx + i) * F_IN + by + tx] = h;
  }
}

// ---- Fused GEMM: [XL|XR][M,5120](f16) = A[M,K](f16) @ BT[5120,K]^T + bias; fp32 acc ----
// ROUND-7 CHANGE: 256x320 tile -> 512 blocks (32m x 16n) = EXACTLY 2 dispatch
// rounds at 1 block/CU. R2-R6's 640 blocks = 3 rounds carrying 2.5 rounds of
// work (640/768 = 83% ceiling; the half-idle 3rd round was the largest single
// identified loss). 2-blocks/CU is impossible at 256-wide tiles (acc=128 VGPR
// alone > 512/4), so fixing the round count is the remaining grid-level lever.
// Per-wave output 128x80: acc[8][5]=160 VGPR (total ~240, fits 2 waves/SIMD).
// LDS 144 KiB: A dbuf 2x32 KiB + B dbuf 2x40 KiB.
// Carried over from R6 (all measured): free-running K-tiles (one vmcnt(0)+
// s_barrier per K-tile, no interior barriers; +6%), per-row XOR-8 16B-chunk
// swizzle (0 conflicts), XCD-chunked bijective grid map (512 = 8x64), setprio
// around MFMA clusters, LDS round-trip epilogue for full-line stores (80-col
// rows have a natural 8-bank row stagger -> no XOR needed there).
__global__ __launch_bounds__(512, 2)
void gemm_fused(const f16* __restrict__ A, const f16* __restrict__ BT,
                const float* __restrict__ bl, const float* __restrict__ br,
                f16* __restrict__ XL, f16* __restrict__ XR)
{
  __shared__ __align__(16) f16 sm[73728];   // 144 KiB
  f16* const sA0 = sm;                      // 256x64 (32 KiB)
  f16* const sA1 = sm + 16384;
  f16* const sB0 = sm + 32768;              // 320x64 (40 KiB)
  f16* const sB1 = sm + 53248;

  const int t    = threadIdx.x;
  const int lane = t & 63;
  const int wave = t >> 6;

  // XCD-local 2D chunk: xcd = bid%8 owns m-tiles [4*xcd, 4*xcd+3] x n 0..15
  const int bid0 = (int)blockIdx.x;      // 512 = 32 m-tiles x 16 n-tiles
  const int xcd  = bid0 & 7;
  const int ic   = bid0 >> 3;            // 0..63, dispatch order within XCD
  const int m0   = (xcd * 4 + (ic & 3)) * 256;   // m-fastest: A panels L2-pinned
  const int n0   = (ic >> 2) * 320;

  const int fm = (wave >> 2) * 128;     // 0 / 128
  const int fn = (wave & 3) * 80;       // 0..240
  const int ml = lane & 15;
  const int lq = lane >> 4;

  auto stageA = [&](f16* D, int kt) {    // 256 rows x 64 k = 2048 slots, 4/thread
    const int k0 = kt * 64;
    #pragma unroll
    for (int jj = 0; jj < 4; ++jj) {
      const int s  = jj * 512 + t;
      const int r  = s >> 3;
      const int lc = (s & 7) ^ (r & 7);
      int gr = m0 + r; gr = (gr < N_NODES) ? gr : (N_NODES - 1);  // clamp pad rows
      const f16* g = A + (size_t)gr * F_IN + k0 + lc * 8;
      __builtin_amdgcn_global_load_lds((AS1 const void*)g,
                                       (AS3 void*)(D + s * 8), 16, 0, 0);
    }
  };
  auto stageB = [&](f16* D, int kt) {    // 320 rows x 64 k = 2560 slots, 5/thread
    const int k0 = kt * 64;
    #pragma unroll
    for (int jj = 0; jj < 5; ++jj) {
      const int s  = jj * 512 + t;
      const int r  = s >> 3;
      const int lc = (s & 7) ^ (r & 7);
      const f16* g = BT + (size_t)(n0 + r) * F_IN + k0 + lc * 8;
      __builtin_amdgcn_global_load_lds((AS1 const void*)g,
                                       (AS3 void*)(D + s * 8), 16, 0, 0);
    }
  };
  auto ldA = [&](const f16* S, int i, int kk) -> f16x8 {
    const int row = fm + i * 16 + ml;
    const int p   = (kk * 4 + lq) ^ (row & 7);
    return *(const f16x8*)(S + row * 64 + p * 8);
  };
  auto ldB = [&](const f16* S, int j, int kk) -> f16x8 {
    const int row = fn + j * 16 + ml;
    const int p   = (kk * 4 + lq) ^ (row & 7);
    return *(const f16x8*)(S + row * 64 + p * 8);
  };

  f32x4 acc[8][5] = {};
  f16x8 bf[5][2];

#define MMROW(i, A0_, A1_)                                                                   \
    _Pragma("unroll")                                                                        \
    for (int j = 0; j < 5; ++j) {                                                            \
      acc[i][j] = __builtin_amdgcn_mfma_f32_16x16x32_f16(A0_, bf[j][0], acc[i][j], 0, 0, 0); \
      acc[i][j] = __builtin_amdgcn_mfma_f32_16x16x32_f16(A1_, bf[j][1], acc[i][j], 0, 0, 0); \
    }

#define SBAR0() __builtin_amdgcn_sched_barrier(0)
#define LOADB(SB) { _Pragma("unroll") for (int j = 0; j < 5; ++j) { bf[j][0] = ldB(SB, j, 0); bf[j][1] = ldB(SB, j, 1); } }

  // prologue: stage tile 0 into buf0, drain, barrier
  stageA(sA0, 0);
  stageB(sB0, 0);
  asm volatile("s_waitcnt vmcnt(0)" ::: "memory");
  __builtin_amdgcn_s_barrier();
  SBAR0();

  for (int T = 0; T < 40; ++T) {
    f16* const rA = (T & 1) ? sA1 : sA0;
    f16* const rB = (T & 1) ? sB1 : sB0;
    f16* const wA = (T & 1) ? sA0 : sA1;
    f16* const wB = (T & 1) ? sB0 : sB1;
    const int Tn = (T + 1 < 40) ? (T + 1) : 39;   // tail: dup stage into dead buf

    LOADB(rB)
    // q0: rows fm+0..31  (stage next A under this quarter's MFMA)
    {
      const f16x8 a00 = ldA(rA, 0, 0), a01 = ldA(rA, 0, 1);
      const f16x8 a10 = ldA(rA, 1, 0), a11 = ldA(rA, 1, 1);
      stageA(wA, Tn);
      __builtin_amdgcn_s_setprio(1);
      MMROW(0, a00, a01)
      MMROW(1, a10, a11)
      __builtin_amdgcn_s_setprio(0);
    }
    SBAR0();
    // q1: rows fm+32..63 (stage next B)
    {
      const f16x8 a00 = ldA(rA, 2, 0), a01 = ldA(rA, 2, 1);
      const f16x8 a10 = ldA(rA, 3, 0), a11 = ldA(rA, 3, 1);
      stageB(wB, Tn);
      __builtin_amdgcn_s_setprio(1);
      MMROW(2, a00, a01)
      MMROW(3, a10, a11)
      __builtin_amdgcn_s_setprio(0);
    }
    SBAR0();
    // q2: rows fm+64..95
    {
      const f16x8 a00 = ldA(rA, 4, 0), a01 = ldA(rA, 4, 1);
      const f16x8 a10 = ldA(rA, 5, 0), a11 = ldA(rA, 5, 1);
      __builtin_amdgcn_s_setprio(1);
      MMROW(4, a00, a01)
      MMROW(5, a10, a11)
      __builtin_amdgcn_s_setprio(0);
    }
    SBAR0();
    // q3: rows fm+96..127
    {
      const f16x8 a00 = ldA(rA, 6, 0), a01 = ldA(rA, 6, 1);
      const f16x8 a10 = ldA(rA, 7, 0), a11 = ldA(rA, 7, 1);
      __builtin_amdgcn_s_setprio(1);
      MMROW(6, a00, a01)
      MMROW(7, a10, a11)
      __builtin_amdgcn_s_setprio(0);
    }
    // K-tile boundary: drain stage-DMA ("memory" clobber fences the compiler:
    // no ds_read of the next tile can hoist above this), then sync.
    asm volatile("s_waitcnt vmcnt(0)" ::: "memory");
    __builtin_amdgcn_s_barrier();
    SBAR0();
  }

#undef MMROW
#undef SBAR0
#undef LOADB

  // ---- epilogue: per-wave LDS round-trip for coalesced 16B stores ----
  __syncthreads();

  const bool left = (n0 < HC);
  f16* __restrict__ OUT = left ? XL : XR;
  const float* __restrict__ bias = left ? bl : br;
  const int nb = left ? n0 : (n0 - HC);
  const int rg = (lane >> 4) * 4;
  f16* const wbase = sm + wave * 5120;   // 10 KiB per wave = 64 rows x 80 cols
  // row stride 160 B = 40 banks ≡ 8 mod 32 -> natural row stagger, no XOR needed.

  #pragma unroll
  for (int rnd = 0; rnd < 2; ++rnd) {
    #pragma unroll
    for (int j = 0; j < 5; ++j) {
      const float bv = bias[nb + fn + j * 16 + ml];
      #pragma unroll
      for (int ii = 0; ii < 4; ++ii) {
        const int i = rnd * 4 + ii;
        #pragma unroll
        for (int r = 0; r < 4; ++r) {
          const int lr  = ii * 16 + rg + r;          // 0..63
          const int col = j * 16 + ml;               // 0..79
          wbase[lr * 80 + col] = (f16)(acc[i][j][r] + bv);
        }
      }
    }
    __syncthreads();
    // cols 0..63 (8 chunks x 8 rows per iter)
    #pragma unroll
    for (int it = 0; it < 8; ++it) {
      const int lr = it * 8 + (lane >> 3);
      const int ch = lane & 7;
      const f16x8 v = *(const f16x8*)(wbase + lr * 80 + ch * 8);
      const int gm = m0 + fm + rnd * 64 + lr;
      if (gm < N_NODES)
        *(f16x8*)(OUT + (size_t)gm * HC + nb + fn + ch * 8) = v;
    }
    // cols 64..79 (2 chunks x 32 rows per iter)
    #pragma unroll
    for (int it = 0; it < 2; ++it) {
      const int lr = it * 32 + (lane >> 1);
      const int ch = 8 + (lane & 1);
      const f16x8 v = *(const f16x8*)(wbase + lr * 80 + ch * 8);
      const int gm = m0 + fm + rnd * 64 + lr;
      if (gm < N_NODES)
        *(f16x8*)(OUT + (size_t)gm * HC + nb + fn + ch * 8) = v;
    }
    __syncthreads();
  }
}

// ---------------- CSR build ----------------
__global__ __launch_bounds__(256)
void count_edges(const int* __restrict__ dst, int* __restrict__ counts)
{
  const int e = blockIdx.x * 256 + threadIdx.x;
  if (e < N_EDGES) atomicAdd(&counts[dst[e]], 1);
}

__global__ __launch_bounds__(256)
void scan_offsets(const int* __restrict__ counts, int* __restrict__ offs, int* __restrict__ cur)
{
  __shared__ int wtot[4];
  const int t = threadIdx.x;
  const int lane = t & 63, wave = t >> 6;
  const int base = t * 32;
  int loc[32];
  int run = 0;
  #pragma unroll
  for (int i = 0; i < 32; ++i) {
    const int idx = base + i;
    const int v = (idx < N_NODES) ? counts[idx] : 0;
    loc[i] = run;
    run += v;
  }
  int incl = run;
  #pragma unroll
  for (int off = 1; off < 64; off <<= 1) {
    int y = __shfl_up(incl, off, 64);
    if (lane >= off) incl += y;
  }
  const int excl = incl - run;
  if (lane == 63) wtot[wave] = incl;
  __syncthreads();
  int wb = 0;
  for (int wv = 0; wv < wave; ++wv) wb += wtot[wv];
  const int mybase = wb + excl;
  #pragma unroll
  for (int i = 0; i < 32; ++i) {
    const int idx = base + i;
    if (idx < N_NODES) { offs[idx] = mybase + loc[i]; cur[idx] = mybase + loc[i]; }
  }
  if (t == 255) offs[N_NODES] = wb + incl;
}

// fill CSR with PACKED edge meta {src, eattr_bits}: one 8B load replaces the
// eids->src/eattr 3-load chain in the edge kernel.
__global__ __launch_bounds__(256)
void fill_csr(const int* __restrict__ dst, const int* __restrict__ srcv,
              const float* __restrict__ ea, int* __restrict__ cur,
              int2* __restrict__ ecsr)
{
  const int e = blockIdx.x * 256 + threadIdx.x;
  if (e < N_EDGES) {
    const int p = atomicAdd(&cur[dst[e]], 1);
    ecsr[p] = make_int2(srcv[e], __float_as_int(ea[e]));
  }
}

// ---- Fused edge phase: scores + online segment-softmax + aggregation, one pass ----
// R2 loop structure (best measured across 4 variants; gather-service bound) +
// packed ecsr meta. Single-edge iteration, ping-pong prefetch.
__global__ __launch_bounds__(256)
void gat_edge_fused(const f16* __restrict__ XL, const f16* __restrict__ XR,
                    const float* __restrict__ We, const float* __restrict__ att,
                    const int2* __restrict__ ecsr, const int* __restrict__ offs,
                    const float* __restrict__ bias,
                    f16* __restrict__ out)
{
  const int n    = blockIdx.x;
  const int t    = threadIdx.x;
  const int wave = t >> 6;
  const int lane = t & 63;
  const int half = lane >> 5;
  const int l32  = lane & 31;
  const int h    = wave * 2 + half;
  const int c8   = h * CPH + l32 * 8;        // 8 contiguous channels (16B aligned)
  const int c2   = h * CPH + 256 + l32 * 2;  // 2 contiguous channels (4B aligned)

  float xr[10], wv[10], av[10];
  {
    const f16x8 v8 = *(const f16x8*)(XR + (size_t)n * HC + c8);
    const f16x2 v2 = *(const f16x2*)(XR + (size_t)n * HC + c2);
    #pragma unroll
    for (int k = 0; k < 8; ++k) xr[k] = (float)v8[k];
    xr[8] = (float)v2[0]; xr[9] = (float)v2[1];
  }
  {
    const float4 w0 = *(const float4*)(We + c8);
    const float4 w1 = *(const float4*)(We + c8 + 4);
    const float4 a0 = *(const float4*)(att + c8);
    const float4 a1 = *(const float4*)(att + c8 + 4);
    wv[0]=w0.x; wv[1]=w0.y; wv[2]=w0.z; wv[3]=w0.w;
    wv[4]=w1.x; wv[5]=w1.y; wv[6]=w1.z; wv[7]=w1.w;
    av[0]=a0.x; av[1]=a0.y; av[2]=a0.z; av[3]=a0.w;
    av[4]=a1.x; av[5]=a1.y; av[6]=a1.z; av[7]=a1.w;
    wv[8] = We[c2]; wv[9] = We[c2 + 1];
    av[8] = att[c2]; av[9] = att[c2 + 1];
  }

  float m = -3.0e38f, l = 0.f;
  float acc[10];
  #pragma unroll
  for (int k = 0; k < 10; ++k) acc[k] = 0.f;

  const int b = offs[n], e = offs[n + 1];
  if (b < e) {
    int2 mA = ecsr[b];
    f16x8 v8A = *(const f16x8*)(XL + (size_t)mA.x * HC + c8);
    f16x2 v2A = *(const f16x2*)(XL + (size_t)mA.x * HC + c2);
    int2 mB = (b + 1 < e) ? ecsr[b + 1] : make_int2(mA.x, 0);

    for (int p = b; p < e; ++p) {
      // prefetch row of p+1 (mB.x valid even past end -> harmless load)
      const f16* rowN = XL + (size_t)mB.x * HC;
      const f16x8 v8N = *(const f16x8*)(rowN + c8);
      const f16x2 v2N = *(const f16x2*)(rowN + c2);
      // prefetch meta of p+2 (clamped -> branch-free)
      const int pn = (p + 2 < e) ? (p + 2) : (e - 1);
      const int2 mC = ecsr[pn];

      // process edge p
      const float ea = __int_as_float(mA.y);
      float xl[10];
      #pragma unroll
      for (int k = 0; k < 8; ++k) xl[k] = (float)v8A[k];
      xl[8] = (float)v2A[0]; xl[9] = (float)v2A[1];
      float partial = 0.f;
      #pragma unroll
      for (int k = 0; k < 10; ++k) {
        float v = xl[k] + xr[k] + ea * wv[k];
        v = (v > 0.f) ? v : SLOPE * v;
        partial += v * av[k];
      }
      #pragma unroll
      for (int msk = 16; msk >= 1; msk >>= 1)
        partial += __shfl_xor(partial, msk, 64);
      const float sc    = partial;
      const float mn    = fmaxf(m, sc);
      const float scale = __expf(m - mn);
      const float w     = __expf(sc - mn);
      l = l * scale + w;
      #pragma unroll
      for (int k = 0; k < 10; ++k) acc[k] = acc[k] * scale + w * xl[k];
      m = mn;

      // shift pipeline
      mA = mB; v8A = v8N; v2A = v2N; mB = mC;
    }
  }

  const float inv = (l > 0.f) ? 1.f / l : 0.f;   // deg-0 node -> out = bias (matches ref)
  f16x8 s8;
  #pragma unroll
  for (int k = 0; k < 8; ++k) s8[k] = (f16)(acc[k] * inv + bias[c8 + k]);
  f16x2 s2;
  s2[0] = (f16)(acc[8] * inv + bias[c2]);
  s2[1] = (f16)(acc[9] * inv + bias[c2 + 1]);
  *(f16x8*)(out + (size_t)n * HC + c8) = s8;
  *(f16x2*)(out + (size_t)n * HC + c2) = s2;
}

// ---------------- global mean pool (batch is sorted), f16 in, f32 out ----------------
__global__ __launch_bounds__(256)
void pool_kernel(const f16* __restrict__ Hm, const int* __restrict__ batch, float* __restrict__ out)
{
  __shared__ int se[2];
  const int g = blockIdx.x;
  const int chunk = blockIdx.y;
  const int t = threadIdx.x;
  if (t < 2) {
    const int target = g + t;
    int lo = 0, hi = N_NODES;
    while (lo < hi) { const int mid = (lo + hi) >> 1; if (batch[mid] < target) lo = mid + 1; else hi = mid; }
    se[t] = lo;
  }
  __syncthreads();
  const int s0 = se[0], s1 = se[1];
  const int c = chunk * 256 + t;
  float sum = 0.f;
  for (int n = s0; n < s1; ++n) sum += (float)Hm[(size_t)n * HC + c];
  int cnt = s1 - s0; if (cnt < 1) cnt = 1;
  out[g * HC + c] = sum / (float)cnt;
}

// ---------------- host: one GATv2 layer (A f16 -> OUT f16) ----------------
static void run_layer(const f16* A, const float* Wl, const float* bl,
                      const float* Wr, const float* br,
                      const float* We, const float* att, const float* bias,
                      f16* WT, f16* XL, f16* XR,
                      const int* offs, const int2* ecsr, f16* OUT, hipStream_t stream)
{
  dim3 tgrid(HC / 64, F_IN / 64);
  transpose_w<<<tgrid, 256, 0, stream>>>(Wl, WT);
  transpose_w<<<tgrid, 256, 0, stream>>>(Wr, WT + (size_t)HC * F_IN);
  gemm_fused<<<32 * (NW / 320), 512, 0, stream>>>(A, WT, bl, br, XL, XR);
  gat_edge_fused<<<N_NODES, 256, 0, stream>>>(XL, XR, We, att, ecsr, offs, bias, OUT);
}

extern "C" void kernel_launch(void* const* d_in, const int* in_sizes, int n_in,
                              void* d_out, int out_size, void* d_ws, size_t ws_size,
                              hipStream_t stream)
{
  const float* x     = (const float*)d_in[0];
  const int*   eidx  = (const int*)d_in[1];
  const float* eattr = (const float*)d_in[2];
  const int*   batch = (const int*)d_in[3];
  const float* Wl1  = (const float*)d_in[4];
  const float* bl1  = (const float*)d_in[5];
  const float* Wr1  = (const float*)d_in[6];
  const float* br1  = (const float*)d_in[7];
  const float* We1  = (const float*)d_in[8];
  const float* att1 = (const float*)d_in[9];
  const float* bias1= (const float*)d_in[10];
  const float* Wl2  = (const float*)d_in[11];
  const float* bl2  = (const float*)d_in[12];
  const float* Wr2  = (const float*)d_in[13];
  const float* br2  = (const float*)d_in[14];
  const float* We2  = (const float*)d_in[15];
  const float* att2 = (const float*)d_in[16];
  const float* bias2= (const float*)d_in[17];
  float* out = (float*)d_out;

  const int* src = eidx;
  const int* dst = eidx + N_EDGES;

  char* w = (char*)d_ws;
  auto take = [&](size_t b) { char* p = w; w += (b + 255) & ~(size_t)255; return p; };
  f16*   Xh    = (f16*)take((size_t)N_NODES * F_IN * 2);   // layer-1 A / layer-1 out (reused)
  f16*   H2h   = (f16*)take((size_t)N_NODES * HC * 2);     // layer-2 out
  f16*   WT    = (f16*)take((size_t)NW * F_IN * 2);        // fused transposed weights
  f16*   XL    = (f16*)take((size_t)N_NODES * HC * 2);
  f16*   XR    = (f16*)take((size_t)N_NODES * HC * 2);
  int*   counts= (int*)take((size_t)N_NODES * 4);
  int*   offs  = (int*)take((size_t)(N_NODES + 1) * 4);
  int*   cur   = (int*)take((size_t)N_NODES * 4);
  int2*  ecsr  = (int2*)take((size_t)N_EDGES * 8);

  hipMemsetAsync(counts, 0, N_NODES * 4, stream);
  count_edges<<<N_EDGES / 256, 256, 0, stream>>>(dst, counts);
  scan_offsets<<<1, 256, 0, stream>>>(counts, offs, cur);
  fill_csr<<<N_EDGES / 256, 256, 0, stream>>>(dst, src, eattr, cur, ecsr);

  cvt_f32_f16<<<(N_NODES * F_IN) / 1024, 256, 0, stream>>>(x, Xh, N_NODES * F_IN);

  // layer 1: Xh -> Xh (edge kernel writes after GEMM has consumed Xh; stream-ordered, safe)
  run_layer(Xh, Wl1, bl1, Wr1, br1, We1, att1, bias1,
            WT, XL, XR, offs, ecsr, Xh, stream);
  // layer 2: Xh -> H2h
  run_layer(Xh, Wl2, bl2, Wr2, br2, We2, att2, bias2,
            WT, XL, XR, offs, ecsr, H2h, stream);

  pool_kernel<<<dim3(NGRAPH, HC / 256), 256, 0, stream>>>(H2h, batch, out);
}

// Round 8
// 857.198 us; speedup vs baseline: 1.0929x; 1.0255x over previous
//
#include <hip/hip_runtime.h>

typedef unsigned short u16;
typedef _Float16 f16;
typedef _Float16 f16x8 __attribute__((ext_vector_type(8)));
typedef _Float16 f16x2 __attribute__((ext_vector_type(2)));
typedef float f32x4 __attribute__((ext_vector_type(4)));

#define AS1 __attribute__((address_space(1)))
#define AS3 __attribute__((address_space(3)))

constexpr int N_NODES = 8000;
constexpr int N_EDGES = 64000;
constexpr int F_IN    = 2560;   // in channels (== H*C, both layers)
constexpr int HEADS   = 8;
constexpr int CPH     = 320;    // channels per head
constexpr int HC      = 2560;   // HEADS*CPH
constexpr int NW      = 5120;   // fused GEMM output width (XL | XR)
constexpr int NGRAPH  = 16;
constexpr float SLOPE = 0.2f;

// ---------------- f32 -> f16 bulk convert (n divisible by 1024) ----------------
__global__ __launch_bounds__(256)
void cvt_f32_f16(const float* __restrict__ in, f16* __restrict__ out, int n)
{
  const int i = (blockIdx.x * 256 + threadIdx.x) * 4;
  if (i >= n) return;
  const float4 v = *(const float4*)(in + i);
  f16 o[4] = {(f16)v.x, (f16)v.y, (f16)v.z, (f16)v.w};
  *(ushort4*)(out + i) = *(const ushort4*)o;
}

// ------ weight transpose + convert: in f32 [R=2560][C=2560] -> out f16 [C][R] ------
__global__ __launch_bounds__(256)
void transpose_w(const float* __restrict__ in, f16* __restrict__ out)
{
  __shared__ u16 tile[64][66];     // +2 pad to break bank stride
  const int bx = blockIdx.x * 64;  // col tile (input)
  const int by = blockIdx.y * 64;  // row tile (input)
  const int tx = threadIdx.x & 63;
  const int ty = threadIdx.x >> 6;
  #pragma unroll
  for (int i = ty; i < 64; i += 4) {
    f16 h = (f16)in[(size_t)(by + i) * HC + bx + tx];
    u16 u; __builtin_memcpy(&u, &h, 2);
    tile[i][tx] = u;
  }
  __syncthreads();
  #pragma unroll
  for (int i = ty; i < 64; i += 4) {
    u16 u = tile[tx][i];
    f16 h; __builtin_memcpy(&h, &u, 2);
    out[(size_t)(bx + i) * F_IN + by + tx] = h;
  }
}

// ---- Fused GEMM: [XL|XR][M,5120](f16) = A[M,K](f16) @ BT[5120,K]^T + bias; fp32 acc ----
// 256x320 tile -> 512 blocks (32m x 16n) = EXACTLY 2 dispatch rounds at
// 1 block/CU (R7: removed the half-idle 3rd round; MfmaUtil 46->50).
// Per-wave output 128x80: acc[8][5]=160 VGPR. LDS 144 KiB (A dbuf 2x32 + B 2x40).
// Free-running K-tiles (one vmcnt(0)+s_barrier per K-tile, no interior
// barriers; R6 +6%), per-row XOR-8 16B-chunk swizzle (0 K-loop conflicts),
// XCD-chunked bijective grid map, setprio around MFMA clusters.
//
// ROUND-8 CHANGE: unified epilogue. R7's per-wave 80-col segments start at
// byte 160*k (not 128-aligned) -> cross-wave partial-line RMW inflated
// WRITE_SIZE 80->122 MB and added 1.8M LDS conflicts (stride-80 reads).
// Now: 4 rounds; each stages a 64-row x 320-col slab into LDS (padded stride
// 328), then ALL 512 threads write full rows -- 640 B = 5 aligned 128B lines.
__global__ __launch_bounds__(512, 2)
void gemm_fused(const f16* __restrict__ A, const f16* __restrict__ BT,
                const float* __restrict__ bl, const float* __restrict__ br,
                f16* __restrict__ XL, f16* __restrict__ XR)
{
  __shared__ __align__(16) f16 sm[73728];   // 144 KiB
  f16* const sA0 = sm;                      // 256x64 (32 KiB)
  f16* const sA1 = sm + 16384;
  f16* const sB0 = sm + 32768;              // 320x64 (40 KiB)
  f16* const sB1 = sm + 53248;

  const int t    = threadIdx.x;
  const int lane = t & 63;
  const int wave = t >> 6;

  // XCD-local 2D chunk: xcd = bid%8 owns m-tiles [4*xcd, 4*xcd+3] x n 0..15
  const int bid0 = (int)blockIdx.x;      // 512 = 32 m-tiles x 16 n-tiles
  const int xcd  = bid0 & 7;
  const int ic   = bid0 >> 3;            // 0..63, dispatch order within XCD
  const int m0   = (xcd * 4 + (ic & 3)) * 256;   // m-fastest: A panels L2-pinned
  const int n0   = (ic >> 2) * 320;

  const int fm = (wave >> 2) * 128;     // 0 / 128
  const int fn = (wave & 3) * 80;       // 0..240
  const int ml = lane & 15;
  const int lq = lane >> 4;

  auto stageA = [&](f16* D, int kt) {    // 256 rows x 64 k = 2048 slots, 4/thread
    const int k0 = kt * 64;
    #pragma unroll
    for (int jj = 0; jj < 4; ++jj) {
      const int s  = jj * 512 + t;
      const int r  = s >> 3;
      const int lc = (s & 7) ^ (r & 7);
      int gr = m0 + r; gr = (gr < N_NODES) ? gr : (N_NODES - 1);  // clamp pad rows
      const f16* g = A + (size_t)gr * F_IN + k0 + lc * 8;
      __builtin_amdgcn_global_load_lds((AS1 const void*)g,
                                       (AS3 void*)(D + s * 8), 16, 0, 0);
    }
  };
  auto stageB = [&](f16* D, int kt) {    // 320 rows x 64 k = 2560 slots, 5/thread
    const int k0 = kt * 64;
    #pragma unroll
    for (int jj = 0; jj < 5; ++jj) {
      const int s  = jj * 512 + t;
      const int r  = s >> 3;
      const int lc = (s & 7) ^ (r & 7);
      const f16* g = BT + (size_t)(n0 + r) * F_IN + k0 + lc * 8;
      __builtin_amdgcn_global_load_lds((AS1 const void*)g,
                                       (AS3 void*)(D + s * 8), 16, 0, 0);
    }
  };
  auto ldA = [&](const f16* S, int i, int kk) -> f16x8 {
    const int row = fm + i * 16 + ml;
    const int p   = (kk * 4 + lq) ^ (row & 7);
    return *(const f16x8*)(S + row * 64 + p * 8);
  };
  auto ldB = [&](const f16* S, int j, int kk) -> f16x8 {
    const int row = fn + j * 16 + ml;
    const int p   = (kk * 4 + lq) ^ (row & 7);
    return *(const f16x8*)(S + row * 64 + p * 8);
  };

  f32x4 acc[8][5] = {};
  f16x8 bf[5][2];

#define MMROW(i, A0_, A1_)                                                                   \
    _Pragma("unroll")                                                                        \
    for (int j = 0; j < 5; ++j) {                                                            \
      acc[i][j] = __builtin_amdgcn_mfma_f32_16x16x32_f16(A0_, bf[j][0], acc[i][j], 0, 0, 0); \
      acc[i][j] = __builtin_amdgcn_mfma_f32_16x16x32_f16(A1_, bf[j][1], acc[i][j], 0, 0, 0); \
    }

#define SBAR0() __builtin_amdgcn_sched_barrier(0)
#define LOADB(SB) { _Pragma("unroll") for (int j = 0; j < 5; ++j) { bf[j][0] = ldB(SB, j, 0); bf[j][1] = ldB(SB, j, 1); } }

  // prologue: stage tile 0 into buf0, drain, barrier
  stageA(sA0, 0);
  stageB(sB0, 0);
  asm volatile("s_waitcnt vmcnt(0)" ::: "memory");
  __builtin_amdgcn_s_barrier();
  SBAR0();

  for (int T = 0; T < 40; ++T) {
    f16* const rA = (T & 1) ? sA1 : sA0;
    f16* const rB = (T & 1) ? sB1 : sB0;
    f16* const wA = (T & 1) ? sA0 : sA1;
    f16* const wB = (T & 1) ? sB0 : sB1;
    const int Tn = (T + 1 < 40) ? (T + 1) : 39;   // tail: dup stage into dead buf

    LOADB(rB)
    // q0: rows fm+0..31  (stage next A under this quarter's MFMA)
    {
      const f16x8 a00 = ldA(rA, 0, 0), a01 = ldA(rA, 0, 1);
      const f16x8 a10 = ldA(rA, 1, 0), a11 = ldA(rA, 1, 1);
      stageA(wA, Tn);
      __builtin_amdgcn_s_setprio(1);
      MMROW(0, a00, a01)
      MMROW(1, a10, a11)
      __builtin_amdgcn_s_setprio(0);
    }
    SBAR0();
    // q1: rows fm+32..63 (stage next B)
    {
      const f16x8 a00 = ldA(rA, 2, 0), a01 = ldA(rA, 2, 1);
      const f16x8 a10 = ldA(rA, 3, 0), a11 = ldA(rA, 3, 1);
      stageB(wB, Tn);
      __builtin_amdgcn_s_setprio(1);
      MMROW(2, a00, a01)
      MMROW(3, a10, a11)
      __builtin_amdgcn_s_setprio(0);
    }
    SBAR0();
    // q2: rows fm+64..95
    {
      const f16x8 a00 = ldA(rA, 4, 0), a01 = ldA(rA, 4, 1);
      const f16x8 a10 = ldA(rA, 5, 0), a11 = ldA(rA, 5, 1);
      __builtin_amdgcn_s_setprio(1);
      MMROW(4, a00, a01)
      MMROW(5, a10, a11)
      __builtin_amdgcn_s_setprio(0);
    }
    SBAR0();
    // q3: rows fm+96..127
    {
      const f16x8 a00 = ldA(rA, 6, 0), a01 = ldA(rA, 6, 1);
      const f16x8 a10 = ldA(rA, 7, 0), a11 = ldA(rA, 7, 1);
      __builtin_amdgcn_s_setprio(1);
      MMROW(6, a00, a01)
      MMROW(7, a10, a11)
      __builtin_amdgcn_s_setprio(0);
    }
    // K-tile boundary: drain stage-DMA ("memory" clobber fences the compiler:
    // no ds_read of the next tile can hoist above this), then sync.
    asm volatile("s_waitcnt vmcnt(0)" ::: "memory");
    __builtin_amdgcn_s_barrier();
    SBAR0();
  }

#undef MMROW
#undef SBAR0
#undef LOADB

  // ---- epilogue: unified 4-round LDS staging -> fully aligned 640B row writes ----
  __syncthreads();

  const bool left = (n0 < HC);
  f16* __restrict__ OUT = left ? XL : XR;
  const float* __restrict__ bias = left ? bl : br;
  const int nb = left ? n0 : (n0 - HC);
  const int rg = (lane >> 4) * 4;
  constexpr int SP = 328;                  // padded LDS row stride (f16)

  #pragma unroll
  for (int r = 0; r < 4; ++r) {
    // round r covers global rows m0 + 64r .. +63; writers: the 4 n-waves of
    // the matching m-half (fm == (r>>1)*128), acc i-indices (r&1)*4 .. +3.
    if (fm == (r >> 1) * 128) {
      const int ih = (r & 1) * 4;
      #pragma unroll
      for (int j = 0; j < 5; ++j) {
        const float bv = bias[nb + fn + j * 16 + ml];
        #pragma unroll
        for (int ii = 0; ii < 4; ++ii) {
          const int i = ih + ii;
          #pragma unroll
          for (int rr = 0; rr < 4; ++rr) {
            const int lr  = ii * 16 + rg + rr;      // 0..63
            const int col = fn + j * 16 + ml;       // 0..319
            sm[lr * SP + col] = (f16)(acc[i][j][rr] + bv);
          }
        }
      }
    }
    __syncthreads();
    // all 512 threads store: 64 rows x 40 16B-chunks = 2560 chunks, 5 passes.
    // each row = contiguous 640 B starting at a 128B-aligned address.
    #pragma unroll
    for (int pass = 0; pass < 5; ++pass) {
      const int s   = pass * 512 + t;       // 0..2559
      const int row = s / 40;
      const int ch  = s - row * 40;
      const f16x8 v = *(const f16x8*)(sm + row * SP + ch * 8);
      const int gm  = m0 + r * 64 + row;
      if (gm < N_NODES)
        *(f16x8*)(OUT + (size_t)gm * HC + nb + ch * 8) = v;
    }
    __syncthreads();
  }
}

// ---------------- CSR build ----------------
__global__ __launch_bounds__(256)
void count_edges(const int* __restrict__ dst, int* __restrict__ counts)
{
  const int e = blockIdx.x * 256 + threadIdx.x;
  if (e < N_EDGES) atomicAdd(&counts[dst[e]], 1);
}

__global__ __launch_bounds__(256)
void scan_offsets(const int* __restrict__ counts, int* __restrict__ offs, int* __restrict__ cur)
{
  __shared__ int wtot[4];
  const int t = threadIdx.x;
  const int lane = t & 63, wave = t >> 6;
  const int base = t * 32;
  int loc[32];
  int run = 0;
  #pragma unroll
  for (int i = 0; i < 32; ++i) {
    const int idx = base + i;
    const int v = (idx < N_NODES) ? counts[idx] : 0;
    loc[i] = run;
    run += v;
  }
  int incl = run;
  #pragma unroll
  for (int off = 1; off < 64; off <<= 1) {
    int y = __shfl_up(incl, off, 64);
    if (lane >= off) incl += y;
  }
  const int excl = incl - run;
  if (lane == 63) wtot[wave] = incl;
  __syncthreads();
  int wb = 0;
  for (int wv = 0; wv < wave; ++wv) wb += wtot[wv];
  const int mybase = wb + excl;
  #pragma unroll
  for (int i = 0; i < 32; ++i) {
    const int idx = base + i;
    if (idx < N_NODES) { offs[idx] = mybase + loc[i]; cur[idx] = mybase + loc[i]; }
  }
  if (t == 255) offs[N_NODES] = wb + incl;
}

// fill CSR with PACKED edge meta {src, eattr_bits}: one 8B load replaces the
// eids->src/eattr 3-load chain in the edge kernel.
__global__ __launch_bounds__(256)
void fill_csr(const int* __restrict__ dst, const int* __restrict__ srcv,
              const float* __restrict__ ea, int* __restrict__ cur,
              int2* __restrict__ ecsr)
{
  const int e = blockIdx.x * 256 + threadIdx.x;
  if (e < N_EDGES) {
    const int p = atomicAdd(&cur[dst[e]], 1);
    ecsr[p] = make_int2(srcv[e], __float_as_int(ea[e]));
  }
}

// ---- Fused edge phase: scores + online segment-softmax + aggregation, one pass ----
// R2 loop structure (best measured across 4 variants; gather-service bound) +
// packed ecsr meta. Single-edge iteration, ping-pong prefetch.
__global__ __launch_bounds__(256)
void gat_edge_fused(const f16* __restrict__ XL, const f16* __restrict__ XR,
                    const float* __restrict__ We, const float* __restrict__ att,
                    const int2* __restrict__ ecsr, const int* __restrict__ offs,
                    const float* __restrict__ bias,
                    f16* __restrict__ out)
{
  const int n    = blockIdx.x;
  const int t    = threadIdx.x;
  const int wave = t >> 6;
  const int lane = t & 63;
  const int half = lane >> 5;
  const int l32  = lane & 31;
  const int h    = wave * 2 + half;
  const int c8   = h * CPH + l32 * 8;        // 8 contiguous channels (16B aligned)
  const int c2   = h * CPH + 256 + l32 * 2;  // 2 contiguous channels (4B aligned)

  float xr[10], wv[10], av[10];
  {
    const f16x8 v8 = *(const f16x8*)(XR + (size_t)n * HC + c8);
    const f16x2 v2 = *(const f16x2*)(XR + (size_t)n * HC + c2);
    #pragma unroll
    for (int k = 0; k < 8; ++k) xr[k] = (float)v8[k];
    xr[8] = (float)v2[0]; xr[9] = (float)v2[1];
  }
  {
    const float4 w0 = *(const float4*)(We + c8);
    const float4 w1 = *(const float4*)(We + c8 + 4);
    const float4 a0 = *(const float4*)(att + c8);
    const float4 a1 = *(const float4*)(att + c8 + 4);
    wv[0]=w0.x; wv[1]=w0.y; wv[2]=w0.z; wv[3]=w0.w;
    wv[4]=w1.x; wv[5]=w1.y; wv[6]=w1.z; wv[7]=w1.w;
    av[0]=a0.x; av[1]=a0.y; av[2]=a0.z; av[3]=a0.w;
    av[4]=a1.x; av[5]=a1.y; av[6]=a1.z; av[7]=a1.w;
    wv[8] = We[c2]; wv[9] = We[c2 + 1];
    av[8] = att[c2]; av[9] = att[c2 + 1];
  }

  float m = -3.0e38f, l = 0.f;
  float acc[10];
  #pragma unroll
  for (int k = 0; k < 10; ++k) acc[k] = 0.f;

  const int b = offs[n], e = offs[n + 1];
  if (b < e) {
    int2 mA = ecsr[b];
    f16x8 v8A = *(const f16x8*)(XL + (size_t)mA.x * HC + c8);
    f16x2 v2A = *(const f16x2*)(XL + (size_t)mA.x * HC + c2);
    int2 mB = (b + 1 < e) ? ecsr[b + 1] : make_int2(mA.x, 0);

    for (int p = b; p < e; ++p) {
      // prefetch row of p+1 (mB.x valid even past end -> harmless load)
      const f16* rowN = XL + (size_t)mB.x * HC;
      const f16x8 v8N = *(const f16x8*)(rowN + c8);
      const f16x2 v2N = *(const f16x2*)(rowN + c2);
      // prefetch meta of p+2 (clamped -> branch-free)
      const int pn = (p + 2 < e) ? (p + 2) : (e - 1);
      const int2 mC = ecsr[pn];

      // process edge p
      const float ea = __int_as_float(mA.y);
      float xl[10];
      #pragma unroll
      for (int k = 0; k < 8; ++k) xl[k] = (float)v8A[k];
      xl[8] = (float)v2A[0]; xl[9] = (float)v2A[1];
      float partial = 0.f;
      #pragma unroll
      for (int k = 0; k < 10; ++k) {
        float v = xl[k] + xr[k] + ea * wv[k];
        v = (v > 0.f) ? v : SLOPE * v;
        partial += v * av[k];
      }
      #pragma unroll
      for (int msk = 16; msk >= 1; msk >>= 1)
        partial += __shfl_xor(partial, msk, 64);
      const float sc    = partial;
      const float mn    = fmaxf(m, sc);
      const float scale = __expf(m - mn);
      const float w     = __expf(sc - mn);
      l = l * scale + w;
      #pragma unroll
      for (int k = 0; k < 10; ++k) acc[k] = acc[k] * scale + w * xl[k];
      m = mn;

      // shift pipeline
      mA = mB; v8A = v8N; v2A = v2N; mB = mC;
    }
  }

  const float inv = (l > 0.f) ? 1.f / l : 0.f;   // deg-0 node -> out = bias (matches ref)
  f16x8 s8;
  #pragma unroll
  for (int k = 0; k < 8; ++k) s8[k] = (f16)(acc[k] * inv + bias[c8 + k]);
  f16x2 s2;
  s2[0] = (f16)(acc[8] * inv + bias[c2]);
  s2[1] = (f16)(acc[9] * inv + bias[c2 + 1]);
  *(f16x8*)(out + (size_t)n * HC + c8) = s8;
  *(f16x2*)(out + (size_t)n * HC + c2) = s2;
}

// ---------------- global mean pool (batch is sorted), f16 in, f32 out ----------------
__global__ __launch_bounds__(256)
void pool_kernel(const f16* __restrict__ Hm, const int* __restrict__ batch, float* __restrict__ out)
{
  __shared__ int se[2];
  const int g = blockIdx.x;
  const int chunk = blockIdx.y;
  const int t = threadIdx.x;
  if (t < 2) {
    const int target = g + t;
    int lo = 0, hi = N_NODES;
    while (lo < hi) { const int mid = (lo + hi) >> 1; if (batch[mid] < target) lo = mid + 1; else hi = mid; }
    se[t] = lo;
  }
  __syncthreads();
  const int s0 = se[0], s1 = se[1];
  const int c = chunk * 256 + t;
  float sum = 0.f;
  for (int n = s0; n < s1; ++n) sum += (float)Hm[(size_t)n * HC + c];
  int cnt = s1 - s0; if (cnt < 1) cnt = 1;
  out[g * HC + c] = sum / (float)cnt;
}

// ---------------- host: one GATv2 layer (A f16 -> OUT f16) ----------------
static void run_layer(const f16* A, const float* Wl, const float* bl,
                      const float* Wr, const float* br,
                      const float* We, const float* att, const float* bias,
                      f16* WT, f16* XL, f16* XR,
                      const int* offs, const int2* ecsr, f16* OUT, hipStream_t stream)
{
  dim3 tgrid(HC / 64, F_IN / 64);
  transpose_w<<<tgrid, 256, 0, stream>>>(Wl, WT);
  transpose_w<<<tgrid, 256, 0, stream>>>(Wr, WT + (size_t)HC * F_IN);
  gemm_fused<<<32 * (NW / 320), 512, 0, stream>>>(A, WT, bl, br, XL, XR);
  gat_edge_fused<<<N_NODES, 256, 0, stream>>>(XL, XR, We, att, ecsr, offs, bias, OUT);
}

extern "C" void kernel_launch(void* const* d_in, const int* in_sizes, int n_in,
                              void* d_out, int out_size, void* d_ws, size_t ws_size,
                              hipStream_t stream)
{
  const float* x     = (const float*)d_in[0];
  const int*   eidx  = (const int*)d_in[1];
  const float* eattr = (const float*)d_in[2];
  const int*   batch = (const int*)d_in[3];
  const float* Wl1  = (const float*)d_in[4];
  const float* bl1  = (const float*)d_in[5];
  const float* Wr1  = (const float*)d_in[6];
  const float* br1  = (const float*)d_in[7];
  const float* We1  = (const float*)d_in[8];
  const float* att1 = (const float*)d_in[9];
  const float* bias1= (const float*)d_in[10];
  const float* Wl2  = (const float*)d_in[11];
  const float* bl2  = (const float*)d_in[12];
  const float* Wr2  = (const float*)d_in[13];
  const float* br2  = (const float*)d_in[14];
  const float* We2  = (const float*)d_in[15];
  const float* att2 = (const float*)d_in[16];
  const float* bias2= (const float*)d_in[17];
  float* out = (float*)d_out;

  const int* src = eidx;
  const int* dst = eidx + N_EDGES;

  char* w = (char*)d_ws;
  auto take = [&](size_t b) { char* p = w; w += (b + 255) & ~(size_t)255; return p; };
  f16*   Xh    = (f16*)take((size_t)N_NODES * F_IN * 2);   // layer-1 A / layer-1 out (reused)
  f16*   H2h   = (f16*)take((size_t)N_NODES * HC * 2);     // layer-2 out
  f16*   WT    = (f16*)take((size_t)NW * F_IN * 2);        // fused transposed weights
  f16*   XL    = (f16*)take((size_t)N_NODES * HC * 2);
  f16*   XR    = (f16*)take((size_t)N_NODES * HC * 2);
  int*   counts= (int*)take((size_t)N_NODES * 4);
  int*   offs  = (int*)take((size_t)(N_NODES + 1) * 4);
  int*   cur   = (int*)take((size_t)N_NODES * 4);
  int2*  ecsr  = (int2*)take((size_t)N_EDGES * 8);

  hipMemsetAsync(counts, 0, N_NODES * 4, stream);
  count_edges<<<N_EDGES / 256, 256, 0, stream>>>(dst, counts);
  scan_offsets<<<1, 256, 0, stream>>>(counts, offs, cur);
  fill_csr<<<N_EDGES / 256, 256, 0, stream>>>(dst, src, eattr, cur, ecsr);

  cvt_f32_f16<<<(N_NODES * F_IN) / 1024, 256, 0, stream>>>(x, Xh, N_NODES * F_IN);

  // layer 1: Xh -> Xh (edge kernel writes after GEMM has consumed Xh; stream-ordered, safe)
  run_layer(Xh, Wl1, bl1, Wr1, br1, We1, att1, bias1,
            WT, XL, XR, offs, ecsr, Xh, stream);
  // layer 2: Xh -> H2h
  run_layer(Xh, Wl2, bl2, Wr2, br2, We2, att2, bias2,
            WT, XL, XR, offs, ecsr, H2h, stream);

  pool_kernel<<<dim3(NGRAPH, HC / 256), 256, 0, stream>>>(H2h, batch, out);
}

// Round 9
// 853.395 us; speedup vs baseline: 1.0978x; 1.0045x over previous
//
#include <hip/hip_runtime.h>

typedef unsigned short u16;
typedef _Float16 f16;
typedef _Float16 f16x8 __attribute__((ext_vector_type(8)));
typedef _Float16 f16x2 __attribute__((ext_vector_type(2)));
typedef float f32x4 __attribute__((ext_vector_type(4)));

#define AS1 __attribute__((address_space(1)))
#define AS3 __attribute__((address_space(3)))

constexpr int N_NODES = 8000;
constexpr int N_EDGES = 64000;
constexpr int F_IN    = 2560;   // in channels (== H*C, both layers)
constexpr int HEADS   = 8;
constexpr int CPH     = 320;    // channels per head
constexpr int HC      = 2560;   // HEADS*CPH
constexpr int NW      = 5120;   // fused GEMM output width (XL | XR)
constexpr int NGRAPH  = 16;
constexpr float SLOPE = 0.2f;

// ---------------- f32 -> f16 bulk convert (n divisible by 1024) ----------------
__global__ __launch_bounds__(256)
void cvt_f32_f16(const float* __restrict__ in, f16* __restrict__ out, int n)
{
  const int i = (blockIdx.x * 256 + threadIdx.x) * 4;
  if (i >= n) return;
  const float4 v = *(const float4*)(in + i);
  f16 o[4] = {(f16)v.x, (f16)v.y, (f16)v.z, (f16)v.w};
  *(ushort4*)(out + i) = *(const ushort4*)o;
}

// ------ weight transpose + convert, VECTORIZED (R9): in f32 [2560][2560] -> f16 [C][R].
// Old version: scalar 4B loads + scalar 2B stores, 4 launches (G13 violation,
// suspected ~35 us each). Now: float4 loads (16B/lane), ushort4 transposed
// stores (8B/lane), pad-66 LDS (<=2-way banks both directions), both weight
// matrices in ONE launch via gridDim.z.
__global__ __launch_bounds__(256)
void transpose_w2(const float* __restrict__ Wl, const float* __restrict__ Wr,
                  f16* __restrict__ out)
{
  __shared__ u16 tile[64][66];     // row stride 66 u16 = 132 B
  const float* __restrict__ in = blockIdx.z ? Wr : Wl;
  f16* __restrict__ o = out + (size_t)blockIdx.z * HC * F_IN;
  const int bx = blockIdx.x * 64;  // input col tile
  const int by = blockIdx.y * 64;  // input row tile
  const int tx = threadIdx.x & 15; // 16 groups x 4 f32 = 64 cols
  const int ty = threadIdx.x >> 4; // 16 rows per pass
  #pragma unroll
  for (int i = 0; i < 4; ++i) {
    const int row = ty + 16 * i;
    const float4 v = *(const float4*)(in + (size_t)(by + row) * HC + bx + tx * 4);
    f16 h0 = (f16)v.x, h1 = (f16)v.y, h2 = (f16)v.z, h3 = (f16)v.w;
    u16 u0, u1, u2, u3;
    __builtin_memcpy(&u0, &h0, 2); __builtin_memcpy(&u1, &h1, 2);
    __builtin_memcpy(&u2, &h2, 2); __builtin_memcpy(&u3, &h3, 2);
    ushort2 w0 = {u0, u1}, w1 = {u2, u3};
    *(ushort2*)&tile[row][tx * 4]     = w0;   // 4B-aligned (132*row + 8*tx)
    *(ushort2*)&tile[row][tx * 4 + 2] = w1;
  }
  __syncthreads();
  // transposed write: thread (c = t>>4, rg = t&15); 16 threads x 8B = 128B lines
  const int c  = threadIdx.x >> 4;
  const int rg = threadIdx.x & 15;
  #pragma unroll
  for (int i = 0; i < 4; ++i) {
    const int col = c + 16 * i;
    ushort4 w;
    w.x = tile[rg * 4 + 0][col];
    w.y = tile[rg * 4 + 1][col];
    w.z = tile[rg * 4 + 2][col];
    w.w = tile[rg * 4 + 3][col];
    *(ushort4*)(o + (size_t)(bx + col) * F_IN + by + rg * 4) = w;
  }
}

// ---- Fused GEMM: [XL|XR][M,5120](f16) = A[M,K](f16) @ BT[5120,K]^T + bias; fp32 acc ----
// 256x320 tile -> 512 blocks (32m x 16n) = EXACTLY 2 dispatch rounds at
// 1 block/CU. Per-wave output 128x80: acc[8][5]=160 VGPR. LDS 144 KiB.
// Free-running K-tiles (one vmcnt(0)+s_barrier per K-tile boundary, no interior
// barriers), per-row XOR-8 16B-chunk swizzle (0 K-loop conflicts), XCD-chunked
// bijective grid map, setprio around MFMA clusters, unified 4-round LDS-staged
// epilogue (640B aligned row writes; R8: conflicts 1.8M->192K, WRITE 122->102MB,
// MfmaUtil 53.5%). FROZEN at R8 (best measured: 185 us).
__global__ __launch_bounds__(512, 2)
void gemm_fused(const f16* __restrict__ A, const f16* __restrict__ BT,
                const float* __restrict__ bl, const float* __restrict__ br,
                f16* __restrict__ XL, f16* __restrict__ XR)
{
  __shared__ __align__(16) f16 sm[73728];   // 144 KiB
  f16* const sA0 = sm;                      // 256x64 (32 KiB)
  f16* const sA1 = sm + 16384;
  f16* const sB0 = sm + 32768;              // 320x64 (40 KiB)
  f16* const sB1 = sm + 53248;

  const int t    = threadIdx.x;
  const int lane = t & 63;
  const int wave = t >> 6;

  // XCD-local 2D chunk: xcd = bid%8 owns m-tiles [4*xcd, 4*xcd+3] x n 0..15
  const int bid0 = (int)blockIdx.x;      // 512 = 32 m-tiles x 16 n-tiles
  const int xcd  = bid0 & 7;
  const int ic   = bid0 >> 3;            // 0..63, dispatch order within XCD
  const int m0   = (xcd * 4 + (ic & 3)) * 256;   // m-fastest: A panels L2-pinned
  const int n0   = (ic >> 2) * 320;

  const int fm = (wave >> 2) * 128;     // 0 / 128
  const int fn = (wave & 3) * 80;       // 0..240
  const int ml = lane & 15;
  const int lq = lane >> 4;

  auto stageA = [&](f16* D, int kt) {    // 256 rows x 64 k = 2048 slots, 4/thread
    const int k0 = kt * 64;
    #pragma unroll
    for (int jj = 0; jj < 4; ++jj) {
      const int s  = jj * 512 + t;
      const int r  = s >> 3;
      const int lc = (s & 7) ^ (r & 7);
      int gr = m0 + r; gr = (gr < N_NODES) ? gr : (N_NODES - 1);  // clamp pad rows
      const f16* g = A + (size_t)gr * F_IN + k0 + lc * 8;
      __builtin_amdgcn_global_load_lds((AS1 const void*)g,
                                       (AS3 void*)(D + s * 8), 16, 0, 0);
    }
  };
  auto stageB = [&](f16* D, int kt) {    // 320 rows x 64 k = 2560 slots, 5/thread
    const int k0 = kt * 64;
    #pragma unroll
    for (int jj = 0; jj < 5; ++jj) {
      const int s  = jj * 512 + t;
      const int r  = s >> 3;
      const int lc = (s & 7) ^ (r & 7);
      const f16* g = BT + (size_t)(n0 + r) * F_IN + k0 + lc * 8;
      __builtin_amdgcn_global_load_lds((AS1 const void*)g,
                                       (AS3 void*)(D + s * 8), 16, 0, 0);
    }
  };
  auto ldA = [&](const f16* S, int i, int kk) -> f16x8 {
    const int row = fm + i * 16 + ml;
    const int p   = (kk * 4 + lq) ^ (row & 7);
    return *(const f16x8*)(S + row * 64 + p * 8);
  };
  auto ldB = [&](const f16* S, int j, int kk) -> f16x8 {
    const int row = fn + j * 16 + ml;
    const int p   = (kk * 4 + lq) ^ (row & 7);
    return *(const f16x8*)(S + row * 64 + p * 8);
  };

  f32x4 acc[8][5] = {};
  f16x8 bf[5][2];

#define MMROW(i, A0_, A1_)                                                                   \
    _Pragma("unroll")                                                                        \
    for (int j = 0; j < 5; ++j) {                                                            \
      acc[i][j] = __builtin_amdgcn_mfma_f32_16x16x32_f16(A0_, bf[j][0], acc[i][j], 0, 0, 0); \
      acc[i][j] = __builtin_amdgcn_mfma_f32_16x16x32_f16(A1_, bf[j][1], acc[i][j], 0, 0, 0); \
    }

#define SBAR0() __builtin_amdgcn_sched_barrier(0)
#define LOADB(SB) { _Pragma("unroll") for (int j = 0; j < 5; ++j) { bf[j][0] = ldB(SB, j, 0); bf[j][1] = ldB(SB, j, 1); } }

  // prologue: stage tile 0 into buf0, drain, barrier
  stageA(sA0, 0);
  stageB(sB0, 0);
  asm volatile("s_waitcnt vmcnt(0)" ::: "memory");
  __builtin_amdgcn_s_barrier();
  SBAR0();

  for (int T = 0; T < 40; ++T) {
    f16* const rA = (T & 1) ? sA1 : sA0;
    f16* const rB = (T & 1) ? sB1 : sB0;
    f16* const wA = (T & 1) ? sA0 : sA1;
    f16* const wB = (T & 1) ? sB0 : sB1;
    const int Tn = (T + 1 < 40) ? (T + 1) : 39;   // tail: dup stage into dead buf

    LOADB(rB)
    // q0: rows fm+0..31  (stage next A under this quarter's MFMA)
    {
      const f16x8 a00 = ldA(rA, 0, 0), a01 = ldA(rA, 0, 1);
      const f16x8 a10 = ldA(rA, 1, 0), a11 = ldA(rA, 1, 1);
      stageA(wA, Tn);
      __builtin_amdgcn_s_setprio(1);
      MMROW(0, a00, a01)
      MMROW(1, a10, a11)
      __builtin_amdgcn_s_setprio(0);
    }
    SBAR0();
    // q1: rows fm+32..63 (stage next B)
    {
      const f16x8 a00 = ldA(rA, 2, 0), a01 = ldA(rA, 2, 1);
      const f16x8 a10 = ldA(rA, 3, 0), a11 = ldA(rA, 3, 1);
      stageB(wB, Tn);
      __builtin_amdgcn_s_setprio(1);
      MMROW(2, a00, a01)
      MMROW(3, a10, a11)
      __builtin_amdgcn_s_setprio(0);
    }
    SBAR0();
    // q2: rows fm+64..95
    {
      const f16x8 a00 = ldA(rA, 4, 0), a01 = ldA(rA, 4, 1);
      const f16x8 a10 = ldA(rA, 5, 0), a11 = ldA(rA, 5, 1);
      __builtin_amdgcn_s_setprio(1);
      MMROW(4, a00, a01)
      MMROW(5, a10, a11)
      __builtin_amdgcn_s_setprio(0);
    }
    SBAR0();
    // q3: rows fm+96..127
    {
      const f16x8 a00 = ldA(rA, 6, 0), a01 = ldA(rA, 6, 1);
      const f16x8 a10 = ldA(rA, 7, 0), a11 = ldA(rA, 7, 1);
      __builtin_amdgcn_s_setprio(1);
      MMROW(6, a00, a01)
      MMROW(7, a10, a11)
      __builtin_amdgcn_s_setprio(0);
    }
    // K-tile boundary: drain stage-DMA ("memory" clobber fences the compiler:
    // no ds_read of the next tile can hoist above this), then sync.
    asm volatile("s_waitcnt vmcnt(0)" ::: "memory");
    __builtin_amdgcn_s_barrier();
    SBAR0();
  }

#undef MMROW
#undef SBAR0
#undef LOADB

  // ---- epilogue: unified 4-round LDS staging -> fully aligned 640B row writes ----
  __syncthreads();

  const bool left = (n0 < HC);
  f16* __restrict__ OUT = left ? XL : XR;
  const float* __restrict__ bias = left ? bl : br;
  const int nb = left ? n0 : (n0 - HC);
  const int rg = (lane >> 4) * 4;
  constexpr int SP = 328;                  // padded LDS row stride (f16)

  #pragma unroll
  for (int r = 0; r < 4; ++r) {
    // round r covers global rows m0 + 64r .. +63; writers: the 4 n-waves of
    // the matching m-half (fm == (r>>1)*128), acc i-indices (r&1)*4 .. +3.
    if (fm == (r >> 1) * 128) {
      const int ih = (r & 1) * 4;
      #pragma unroll
      for (int j = 0; j < 5; ++j) {
        const float bv = bias[nb + fn + j * 16 + ml];
        #pragma unroll
        for (int ii = 0; ii < 4; ++ii) {
          const int i = ih + ii;
          #pragma unroll
          for (int rr = 0; rr < 4; ++rr) {
            const int lr  = ii * 16 + rg + rr;      // 0..63
            const int col = fn + j * 16 + ml;       // 0..319
            sm[lr * SP + col] = (f16)(acc[i][j][rr] + bv);
          }
        }
      }
    }
    __syncthreads();
    // all 512 threads store: 64 rows x 40 16B-chunks = 2560 chunks, 5 passes.
    // each row = contiguous 640 B starting at a 128B-aligned address.
    #pragma unroll
    for (int pass = 0; pass < 5; ++pass) {
      const int s   = pass * 512 + t;       // 0..2559
      const int row = s / 40;
      const int ch  = s - row * 40;
      const f16x8 v = *(const f16x8*)(sm + row * SP + ch * 8);
      const int gm  = m0 + r * 64 + row;
      if (gm < N_NODES)
        *(f16x8*)(OUT + (size_t)gm * HC + nb + ch * 8) = v;
    }
    __syncthreads();
  }
}

// ---------------- CSR build ----------------
__global__ __launch_bounds__(256)
void count_edges(const int* __restrict__ dst, int* __restrict__ counts)
{
  const int e = blockIdx.x * 256 + threadIdx.x;
  if (e < N_EDGES) atomicAdd(&counts[dst[e]], 1);
}

__global__ __launch_bounds__(256)
void scan_offsets(const int* __restrict__ counts, int* __restrict__ offs, int* __restrict__ cur)
{
  __shared__ int wtot[4];
  const int t = threadIdx.x;
  const int lane = t & 63, wave = t >> 6;
  const int base = t * 32;
  int loc[32];
  int run = 0;
  #pragma unroll
  for (int i = 0; i < 32; ++i) {
    const int idx = base + i;
    const int v = (idx < N_NODES) ? counts[idx] : 0;
    loc[i] = run;
    run += v;
  }
  int incl = run;
  #pragma unroll
  for (int off = 1; off < 64; off <<= 1) {
    int y = __shfl_up(incl, off, 64);
    if (lane >= off) incl += y;
  }
  const int excl = incl - run;
  if (lane == 63) wtot[wave] = incl;
  __syncthreads();
  int wb = 0;
  for (int wv = 0; wv < wave; ++wv) wb += wtot[wv];
  const int mybase = wb + excl;
  #pragma unroll
  for (int i = 0; i < 32; ++i) {
    const int idx = base + i;
    if (idx < N_NODES) { offs[idx] = mybase + loc[i]; cur[idx] = mybase + loc[i]; }
  }
  if (t == 255) offs[N_NODES] = wb + incl;
}

// fill CSR with PACKED edge meta {src, eattr_bits}: one 8B load replaces the
// eids->src/eattr 3-load chain in the edge kernel.
__global__ __launch_bounds__(256)
void fill_csr(const int* __restrict__ dst, const int* __restrict__ srcv,
              const float* __restrict__ ea, int* __restrict__ cur,
              int2* __restrict__ ecsr)
{
  const int e = blockIdx.x * 256 + threadIdx.x;
  if (e < N_EDGES) {
    const int p = atomicAdd(&cur[dst[e]], 1);
    ecsr[p] = make_int2(srcv[e], __float_as_int(ea[e]));
  }
}

// ---- Fused edge phase: scores + online segment-softmax + aggregation, one pass ----
// R2 loop structure (best measured across 4 variants; gather-service bound) +
// packed ecsr meta. Single-edge iteration, ping-pong prefetch. FROZEN.
__global__ __launch_bounds__(256)
void gat_edge_fused(const f16* __restrict__ XL, const f16* __restrict__ XR,
                    const float* __restrict__ We, const float* __restrict__ att,
                    const int2* __restrict__ ecsr, const int* __restrict__ offs,
                    const float* __restrict__ bias,
                    f16* __restrict__ out)
{
  const int n    = blockIdx.x;
  const int t    = threadIdx.x;
  const int wave = t >> 6;
  const int lane = t & 63;
  const int half = lane >> 5;
  const int l32  = lane & 31;
  const int h    = wave * 2 + half;
  const int c8   = h * CPH + l32 * 8;        // 8 contiguous channels (16B aligned)
  const int c2   = h * CPH + 256 + l32 * 2;  // 2 contiguous channels (4B aligned)

  float xr[10], wv[10], av[10];
  {
    const f16x8 v8 = *(const f16x8*)(XR + (size_t)n * HC + c8);
    const f16x2 v2 = *(const f16x2*)(XR + (size_t)n * HC + c2);
    #pragma unroll
    for (int k = 0; k < 8; ++k) xr[k] = (float)v8[k];
    xr[8] = (float)v2[0]; xr[9] = (float)v2[1];
  }
  {
    const float4 w0 = *(const float4*)(We + c8);
    const float4 w1 = *(const float4*)(We + c8 + 4);
    const float4 a0 = *(const float4*)(att + c8);
    const float4 a1 = *(const float4*)(att + c8 + 4);
    wv[0]=w0.x; wv[1]=w0.y; wv[2]=w0.z; wv[3]=w0.w;
    wv[4]=w1.x; wv[5]=w1.y; wv[6]=w1.z; wv[7]=w1.w;
    av[0]=a0.x; av[1]=a0.y; av[2]=a0.z; av[3]=a0.w;
    av[4]=a1.x; av[5]=a1.y; av[6]=a1.z; av[7]=a1.w;
    wv[8] = We[c2]; wv[9] = We[c2 + 1];
    av[8] = att[c2]; av[9] = att[c2 + 1];
  }

  float m = -3.0e38f, l = 0.f;
  float acc[10];
  #pragma unroll
  for (int k = 0; k < 10; ++k) acc[k] = 0.f;

  const int b = offs[n], e = offs[n + 1];
  if (b < e) {
    int2 mA = ecsr[b];
    f16x8 v8A = *(const f16x8*)(XL + (size_t)mA.x * HC + c8);
    f16x2 v2A = *(const f16x2*)(XL + (size_t)mA.x * HC + c2);
    int2 mB = (b + 1 < e) ? ecsr[b + 1] : make_int2(mA.x, 0);

    for (int p = b; p < e; ++p) {
      // prefetch row of p+1 (mB.x valid even past end -> harmless load)
      const f16* rowN = XL + (size_t)mB.x * HC;
      const f16x8 v8N = *(const f16x8*)(rowN + c8);
      const f16x2 v2N = *(const f16x2*)(rowN + c2);
      // prefetch meta of p+2 (clamped -> branch-free)
      const int pn = (p + 2 < e) ? (p + 2) : (e - 1);
      const int2 mC = ecsr[pn];

      // process edge p
      const float ea = __int_as_float(mA.y);
      float xl[10];
      #pragma unroll
      for (int k = 0; k < 8; ++k) xl[k] = (float)v8A[k];
      xl[8] = (float)v2A[0]; xl[9] = (float)v2A[1];
      float partial = 0.f;
      #pragma unroll
      for (int k = 0; k < 10; ++k) {
        float v = xl[k] + xr[k] + ea * wv[k];
        v = (v > 0.f) ? v : SLOPE * v;
        partial += v * av[k];
      }
      #pragma unroll
      for (int msk = 16; msk >= 1; msk >>= 1)
        partial += __shfl_xor(partial, msk, 64);
      const float sc    = partial;
      const float mn    = fmaxf(m, sc);
      const float scale = __expf(m - mn);
      const float w     = __expf(sc - mn);
      l = l * scale + w;
      #pragma unroll
      for (int k = 0; k < 10; ++k) acc[k] = acc[k] * scale + w * xl[k];
      m = mn;

      // shift pipeline
      mA = mB; v8A = v8N; v2A = v2N; mB = mC;
    }
  }

  const float inv = (l > 0.f) ? 1.f / l : 0.f;   // deg-0 node -> out = bias (matches ref)
  f16x8 s8;
  #pragma unroll
  for (int k = 0; k < 8; ++k) s8[k] = (f16)(acc[k] * inv + bias[c8 + k]);
  f16x2 s2;
  s2[0] = (f16)(acc[8] * inv + bias[c2]);
  s2[1] = (f16)(acc[9] * inv + bias[c2 + 1]);
  *(f16x8*)(out + (size_t)n * HC + c8) = s8;
  *(f16x2*)(out + (size_t)n * HC + c2) = s2;
}

// ---------------- global mean pool (batch is sorted), f16 in, f32 out ----------------
// R9: 2 channels/thread via one 4B load (grid.y 10 -> 5), halves load instrs.
__global__ __launch_bounds__(256)
void pool_kernel(const f16* __restrict__ Hm, const int* __restrict__ batch, float* __restrict__ out)
{
  __shared__ int se[2];
  const int g = blockIdx.x;
  const int t = threadIdx.x;
  if (t < 2) {
    const int target = g + t;
    int lo = 0, hi = N_NODES;
    while (lo < hi) { const int mid = (lo + hi) >> 1; if (batch[mid] < target) lo = mid + 1; else hi = mid; }
    se[t] = lo;
  }
  __syncthreads();
  const int s0 = se[0], s1 = se[1];
  const int c = (blockIdx.y * 256 + t) * 2;
  float sum0 = 0.f, sum1 = 0.f;
  for (int n = s0; n < s1; ++n) {
    const f16x2 v = *(const f16x2*)(Hm + (size_t)n * HC + c);
    sum0 += (float)v[0];
    sum1 += (float)v[1];
  }
  int cnt = s1 - s0; if (cnt < 1) cnt = 1;
  const float inv = 1.f / (float)cnt;
  out[g * HC + c]     = sum0 * inv;
  out[g * HC + c + 1] = sum1 * inv;
}

// ---------------- host: one GATv2 layer (A f16 -> OUT f16) ----------------
static void run_layer(const f16* A, const float* Wl, const float* bl,
                      const float* Wr, const float* br,
                      const float* We, const float* att, const float* bias,
                      f16* WT, f16* XL, f16* XR,
                      const int* offs, const int2* ecsr, f16* OUT, hipStream_t stream)
{
  transpose_w2<<<dim3(HC / 64, F_IN / 64, 2), 256, 0, stream>>>(Wl, Wr, WT);
  gemm_fused<<<32 * (NW / 320), 512, 0, stream>>>(A, WT, bl, br, XL, XR);
  gat_edge_fused<<<N_NODES, 256, 0, stream>>>(XL, XR, We, att, ecsr, offs, bias, OUT);
}

extern "C" void kernel_launch(void* const* d_in, const int* in_sizes, int n_in,
                              void* d_out, int out_size, void* d_ws, size_t ws_size,
                              hipStream_t stream)
{
  const float* x     = (const float*)d_in[0];
  const int*   eidx  = (const int*)d_in[1];
  const float* eattr = (const float*)d_in[2];
  const int*   batch = (const int*)d_in[3];
  const float* Wl1  = (const float*)d_in[4];
  const float* bl1  = (const float*)d_in[5];
  const float* Wr1  = (const float*)d_in[6];
  const float* br1  = (const float*)d_in[7];
  const float* We1  = (const float*)d_in[8];
  const float* att1 = (const float*)d_in[9];
  const float* bias1= (const float*)d_in[10];
  const float* Wl2  = (const float*)d_in[11];
  const float* bl2  = (const float*)d_in[12];
  const float* Wr2  = (const float*)d_in[13];
  const float* br2  = (const float*)d_in[14];
  const float* We2  = (const float*)d_in[15];
  const float* att2 = (const float*)d_in[16];
  const float* bias2= (const float*)d_in[17];
  float* out = (float*)d_out;

  const int* src = eidx;
  const int* dst = eidx + N_EDGES;

  char* w = (char*)d_ws;
  auto take = [&](size_t b) { char* p = w; w += (b + 255) & ~(size_t)255; return p; };
  f16*   Xh    = (f16*)take((size_t)N_NODES * F_IN * 2);   // layer-1 A / layer-1 out (reused)
  f16*   H2h   = (f16*)take((size_t)N_NODES * HC * 2);     // layer-2 out
  f16*   WT    = (f16*)take((size_t)NW * F_IN * 2);        // fused transposed weights
  f16*   XL    = (f16*)take((size_t)N_NODES * HC * 2);
  f16*   XR    = (f16*)take((size_t)N_NODES * HC * 2);
  int*   counts= (int*)take((size_t)N_NODES * 4);
  int*   offs  = (int*)take((size_t)(N_NODES + 1) * 4);
  int*   cur   = (int*)take((size_t)N_NODES * 4);
  int2*  ecsr  = (int2*)take((size_t)N_EDGES * 8);

  hipMemsetAsync(counts, 0, N_NODES * 4, stream);
  count_edges<<<N_EDGES / 256, 256, 0, stream>>>(dst, counts);
  scan_offsets<<<1, 256, 0, stream>>>(counts, offs, cur);
  fill_csr<<<N_EDGES / 256, 256, 0, stream>>>(dst, src, eattr, cur, ecsr);

  cvt_f32_f16<<<(N_NODES * F_IN) / 1024, 256, 0, stream>>>(x, Xh, N_NODES * F_IN);

  // layer 1: Xh -> Xh (edge kernel writes after GEMM has consumed Xh; stream-ordered, safe)
  run_layer(Xh, Wl1, bl1, Wr1, br1, We1, att1, bias1,
            WT, XL, XR, offs, ecsr, Xh, stream);
  // layer 2: Xh -> H2h
  run_layer(Xh, Wl2, bl2, Wr2, br2, We2, att2, bias2,
            WT, XL, XR, offs, ecsr, H2h, stream);

  pool_kernel<<<dim3(NGRAPH, HC / 512), 256, 0, stream>>>(H2h, batch, out);
}